// Round 1
// baseline (2454.099 us; speedup 1.0000x reference)
//
#include <hip/hip_runtime.h>
#include <cstddef>

#define H 128

// ---------------- helpers ----------------
__device__ __forceinline__ unsigned fkey(float f){
    unsigned u = __float_as_uint(f);
    return (u & 0x80000000u) ? ~u : (u | 0x80000000u);
}
__device__ __forceinline__ float funkey(unsigned k){
    unsigned u = (k & 0x80000000u) ? (k ^ 0x80000000u) : ~k;
    return __uint_as_float(u);
}

// ---------------- embeddings ----------------
__global__ __launch_bounds__(256) void k_embed_place(
    const float* __restrict__ pf, const float* __restrict__ Wpe,
    const float* __restrict__ bpe, float* __restrict__ out, int P)
{
    int idx = blockIdx.x*256 + threadIdx.x;     // float4 index over P*32
    if (idx >= P*32) return;
    int p = idx >> 5, q = (idx & 31) << 2;
    float v = pf[p];
    float4 w = *(const float4*)(Wpe + q);
    float4 b = *(const float4*)(bpe + q);
    float4 o;
    o.x = v*w.x + b.x; o.y = v*w.y + b.y; o.z = v*w.z + b.z; o.w = v*w.w + b.w;
    *(float4*)(out + (size_t)p*H + q) = o;
}

__global__ __launch_bounds__(256) void k_embed_trans(
    const float* __restrict__ tf, const float* __restrict__ Wte,
    const float* __restrict__ bte, float* __restrict__ out, int T)
{
    __shared__ float Wl[8*H];
    __shared__ float Bl[H];
    int tid = threadIdx.x;
    #pragma unroll
    for (int t = 0; t < 4; t++) Wl[tid + t*256] = Wte[tid + t*256];
    if (tid < H) Bl[tid] = bte[tid];
    __syncthreads();
    int idx = blockIdx.x*256 + tid;
    if (idx >= T*32) return;
    int t = idx >> 5, q = (idx & 31) << 2;
    float4 acc = *(float4*)(&Bl[q]);
    #pragma unroll
    for (int k = 0; k < 8; k++){
        float s = tf[(size_t)t*8 + k];
        float4 w = *(float4*)(&Wl[k*H + q]);
        acc.x += s*w.x; acc.y += s*w.y; acc.z += s*w.z; acc.w += s*w.w;
    }
    *(float4*)(out + (size_t)t*H + q) = acc;
}

// prefix embedding + zero small accumulators (ws is poisoned each call)
__global__ void k_init_small(const float* __restrict__ pe, int plen,
                             const float* __restrict__ Wpr, const float* __restrict__ bpr,
                             float* __restrict__ prefix, float* __restrict__ meanP,
                             float* __restrict__ meanT)
{
    int c = threadIdx.x;  // 128 threads
    float a = bpr[c];
    for (int k = 0; k < plen; k++) a += pe[k]*Wpr[k*H + c];
    prefix[c] = a;
    meanP[c] = 0.f;
    meanT[c] = 0.f;
}

// ---------------- generic fused GEMM ----------------
// out[M,128] = maybe_relu( maybe(resid) + [A1 | A2] @ W + bias )
// A1,A2: [M,128] each (A2 used for K=256). W: [K,128] row-major.
// BM=64, BN=128, BK=32; 256 threads; 4x8 register tile per thread.
__global__ __launch_bounds__(256) void k_gemm(
    const float* __restrict__ A1, const float* __restrict__ A2,
    const float* __restrict__ W, const float* __restrict__ bias,
    const float* __restrict__ resid, float* __restrict__ out,
    int M, int K, int relu, unsigned* initp)
{
    __shared__ float As[64*36];     // +4 pad breaks 4-way bank conflicts, keeps 16B align
    __shared__ float Ws[32*H];
    int tid = threadIdx.x;
    if (initp != nullptr && blockIdx.x == 0 && tid == 0){
        initp[0] = 0u;                  // softmax max accumulator (encoded-uint key)
        ((float*)initp)[1] = 0.f;       // softmax sum accumulator
    }
    int row0 = blockIdx.x * 64;
    int tc = tid & 15, tr = tid >> 4;
    float acc[4][8];
    #pragma unroll
    for (int i = 0; i < 4; i++)
        #pragma unroll
        for (int j = 0; j < 8; j++) acc[i][j] = 0.f;

    for (int k0 = 0; k0 < K; k0 += 32){
        const float* Asrc = (k0 < H) ? A1 : A2;
        int kl = k0 & (H-1);
        #pragma unroll
        for (int t = 0; t < 2; t++){
            int f = tid + t*256;
            int r = f >> 3, kq = (f & 7) << 2;
            int rg = row0 + r;
            float4 v = make_float4(0.f, 0.f, 0.f, 0.f);
            if (rg < M) v = *(const float4*)(Asrc + (size_t)rg*H + kl + kq);
            *(float4*)(&As[r*36 + kq]) = v;
        }
        #pragma unroll
        for (int t = 0; t < 4; t++){
            int f = tid + t*256;
            int k = f >> 5, cq = (f & 31) << 2;
            *(float4*)(&Ws[k*H + cq]) = *(const float4*)(W + (size_t)(k0 + k)*H + cq);
        }
        __syncthreads();
        #pragma unroll
        for (int k = 0; k < 32; k++){
            float av[4];
            #pragma unroll
            for (int i = 0; i < 4; i++) av[i] = As[(tr*4 + i)*36 + k];
            float4 w0 = *(float4*)(&Ws[k*H + tc*4]);
            float4 w1 = *(float4*)(&Ws[k*H + 64 + tc*4]);
            #pragma unroll
            for (int i = 0; i < 4; i++){
                acc[i][0] += av[i]*w0.x; acc[i][1] += av[i]*w0.y;
                acc[i][2] += av[i]*w0.z; acc[i][3] += av[i]*w0.w;
                acc[i][4] += av[i]*w1.x; acc[i][5] += av[i]*w1.y;
                acc[i][6] += av[i]*w1.z; acc[i][7] += av[i]*w1.w;
            }
        }
        __syncthreads();
    }
    #pragma unroll
    for (int i = 0; i < 4; i++){
        int rg = row0 + tr*4 + i;
        if (rg >= M) continue;
        #pragma unroll
        for (int hh = 0; hh < 2; hh++){
            int c = hh*64 + tc*4;
            float4 v;
            v.x = acc[i][hh*4+0] + bias[c+0];
            v.y = acc[i][hh*4+1] + bias[c+1];
            v.z = acc[i][hh*4+2] + bias[c+2];
            v.w = acc[i][hh*4+3] + bias[c+3];
            if (resid){
                float4 rv = *(const float4*)(resid + (size_t)rg*H + c);
                v.x += rv.x; v.y += rv.y; v.z += rv.z; v.w += rv.w;
            }
            if (relu){
                v.x = fmaxf(v.x, 0.f); v.y = fmaxf(v.y, 0.f);
                v.z = fmaxf(v.z, 0.f); v.w = fmaxf(v.w, 0.f);
            }
            *(float4*)(out + (size_t)rg*H + c) = v;
        }
    }
}

// ---------------- per-node attention score + node max ----------------
// y[i] = dot(X[i,:], aw) + ab ; Mkey = encoded max over nodes (>= edge max, safe shift)
__global__ __launch_bounds__(256) void k_score(
    const float* __restrict__ X, const float* __restrict__ aw,
    const float* __restrict__ abp, float* __restrict__ y, int N, unsigned* Mkey)
{
    __shared__ float awl[H];
    __shared__ float wmax[4];
    int tid = threadIdx.x;
    if (tid < H) awl[tid] = aw[tid];
    __syncthreads();
    int lane = tid & 63, w = tid >> 6;
    int gw = blockIdx.x*4 + w, nw = gridDim.x*4;
    float ab = abp[0];
    float lmax = -3.402823466e38f;
    for (int r = gw; r < N; r += nw){
        float v = X[(size_t)r*H + lane]*awl[lane] + X[(size_t)r*H + 64 + lane]*awl[64 + lane];
        #pragma unroll
        for (int o = 32; o > 0; o >>= 1) v += __shfl_xor(v, o);
        float s = v + ab;
        if (lane == 0) y[r] = s;
        lmax = fmaxf(lmax, s);
    }
    if (lane == 0) wmax[w] = lmax;
    __syncthreads();
    if (tid == 0){
        float m = fmaxf(fmaxf(wmax[0], wmax[1]), fmaxf(wmax[2], wmax[3]));
        atomicMax(Mkey, fkey(m));
    }
}

// ---------------- softmax denominator over edges + zero msg buffer ----------------
__global__ __launch_bounds__(256) void k_sumexp_zero(
    const int* __restrict__ src, int E, const float* __restrict__ y,
    const unsigned* __restrict__ Mkey, float* __restrict__ Sp,
    float4* __restrict__ zbuf, int zN4)
{
    __shared__ float red[256];
    int tid = threadIdx.x;
    int gid = blockIdx.x*256 + tid, stride = gridDim.x*256;
    float M = funkey(Mkey[0]);
    float ls = 0.f;
    for (int e = gid; e < E; e += stride) ls += expf(y[src[e]] - M);
    red[tid] = ls;
    // zero the message buffer while the reduction tree syncs
    float4 z = make_float4(0.f, 0.f, 0.f, 0.f);
    for (int i = gid; i < zN4; i += stride) zbuf[i] = z;
    __syncthreads();
    for (int s = 128; s > 0; s >>= 1){
        if (tid < s) red[tid] += red[tid + s];
        __syncthreads();
    }
    if (tid == 0) atomicAdd(Sp, red[0]);
}

// ---------------- weighted scatter: msg[dst] += softmax(e) * X[src] ----------------
__global__ __launch_bounds__(256) void k_scatter(
    const int* __restrict__ src, const int* __restrict__ dst, int E,
    const float* __restrict__ y, const float* __restrict__ X,
    float* __restrict__ Mb, const unsigned* __restrict__ Mkey,
    const float* __restrict__ Sp)
{
    int tid = threadIdx.x;
    int lane = tid & 63, w = tid >> 6;
    int gw = blockIdx.x*4 + w, nw = gridDim.x*4;
    float M = funkey(Mkey[0]);
    float invS = 1.f / Sp[0];
    for (int e = gw; e < E; e += nw){
        int s = src[e], d = dst[e];
        float wg = expf(y[s] - M) * invS;
        float x0 = X[(size_t)s*H + lane];
        float x1 = X[(size_t)s*H + 64 + lane];
        atomicAdd(&Mb[(size_t)d*H + lane],      wg*x0);
        atomicAdd(&Mb[(size_t)d*H + 64 + lane], wg*x1);
    }
}

// ---------------- column mean accumulator (pooling is linear) ----------------
__global__ __launch_bounds__(256) void k_colmean(
    const float* __restrict__ h, int N, float* __restrict__ accum)
{
    __shared__ float cs[256];
    int tid = threadIdx.x;
    int c = tid & 127, rr = tid >> 7;
    float a = 0.f;
    for (int r = blockIdx.x*2 + rr; r < N; r += gridDim.x*2)
        a += h[(size_t)r*H + c];
    cs[tid] = a;
    __syncthreads();
    if (tid < 128) atomicAdd(&accum[c], cs[tid] + cs[tid + 128]);
}

// ---------------- tiny MLP head (pool->W_pp/W_tp, concat, W1, W2) ----------------
__global__ __launch_bounds__(256) void k_head(
    const float* __restrict__ meanP, const float* __restrict__ meanT,
    float invP, float invT,
    const float* __restrict__ Wpp, const float* __restrict__ bpp,
    const float* __restrict__ Wtp, const float* __restrict__ btp,
    const float* __restrict__ prefix,
    const float* __restrict__ W1, const float* __restrict__ b1,
    const float* __restrict__ W2, const float* __restrict__ b2,
    float* __restrict__ h2g)
{
    __shared__ float comb[384];
    __shared__ float h1s[256];
    int tid = threadIdx.x;
    if (tid < 128){
        float a = bpp[tid];
        for (int k = 0; k < 128; k++) a += meanP[k]*invP*Wpp[k*H + tid];
        comb[tid] = a;
        comb[256 + tid] = prefix[tid];
    } else {
        int c = tid - 128;
        float a = btp[c];
        for (int k = 0; k < 128; k++) a += meanT[k]*invT*Wtp[k*H + c];
        comb[128 + c] = a;
    }
    __syncthreads();
    {
        float a = b1[tid];
        for (int k = 0; k < 384; k++) a += comb[k]*W1[k*256 + tid];
        h1s[tid] = fmaxf(a, 0.f);
    }
    __syncthreads();
    if (tid < 128){
        float a = b2[tid];
        for (int k = 0; k < 256; k++) a += h1s[k]*W2[k*H + tid];
        h2g[tid] = fmaxf(a, 0.f);
    }
}

// ---------------- logits + sigmoid ----------------
__global__ __launch_bounds__(256) void k_logits(
    const float* __restrict__ h2g, const float* __restrict__ W3,
    const float* __restrict__ b3, float* __restrict__ out, int T)
{
    __shared__ float h2l[128];
    int tid = threadIdx.x;
    if (tid < 128) h2l[tid] = h2g[tid];
    __syncthreads();
    int t = blockIdx.x*256 + tid;
    if (t >= T) return;
    float a = b3[t];
    #pragma unroll 8
    for (int k = 0; k < 128; k++) a += h2l[k]*W3[(size_t)k*T + t];
    out[t] = 1.f/(1.f + expf(-a));
}

// ---------------- launch ----------------
extern "C" void kernel_launch(void* const* d_in, const int* in_sizes, int n_in,
                              void* d_out, int out_size, void* d_ws, size_t ws_size,
                              hipStream_t stream)
{
    (void)n_in; (void)out_size; (void)ws_size;
    const float* pf    = (const float*)d_in[0];
    const float* tf    = (const float*)d_in[1];
    const float* pe    = (const float*)d_in[2];
    const int*   pre   = (const int*)d_in[3];
    const int*   post  = (const int*)d_in[4];
    const float* W_pe  = (const float*)d_in[5];
    const float* b_pe  = (const float*)d_in[6];
    const float* W_te  = (const float*)d_in[7];
    const float* b_te  = (const float*)d_in[8];
    const float* W_pr  = (const float*)d_in[9];
    const float* b_pr  = (const float*)d_in[10];
    const float* p2t_W = (const float*)d_in[11];
    const float* p2t_b = (const float*)d_in[12];
    const float* t2p_W = (const float*)d_in[13];
    const float* t2p_b = (const float*)d_in[14];
    const float* pu_W  = (const float*)d_in[15];
    const float* pu_b  = (const float*)d_in[16];
    const float* tu_W  = (const float*)d_in[17];
    const float* tu_b  = (const float*)d_in[18];
    const float* pa_W  = (const float*)d_in[19];
    const float* pa_b  = (const float*)d_in[20];
    const float* ta_W  = (const float*)d_in[21];
    const float* ta_b  = (const float*)d_in[22];
    const float* W_pp  = (const float*)d_in[23];
    const float* b_pp  = (const float*)d_in[24];
    const float* W_tp  = (const float*)d_in[25];
    const float* b_tp  = (const float*)d_in[26];
    const float* W1    = (const float*)d_in[27];
    const float* b1    = (const float*)d_in[28];
    const float* W2    = (const float*)d_in[29];
    const float* b2    = (const float*)d_in[30];
    const float* W3    = (const float*)d_in[31];
    const float* b3    = (const float*)d_in[32];

    int P = in_sizes[0];
    int T = in_sizes[1] / 8;
    int E = in_sizes[3] / 2;
    int plen = in_sizes[2];
    int L = in_sizes[11] / (H*H);

    float* ws = (float*)d_ws;
    size_t fP = (size_t)P*H, fT = (size_t)T*H;
    size_t fN = (fP > fT) ? fP : fT;
    int   Nmax = (P > T) ? P : T;
    float* place_h = ws;
    float* trans_h = place_h + fP;
    float* Xb      = trans_h + fT;
    float* Mb      = Xb + fN;
    float* yb      = Mb + fN;
    float* sc      = yb + Nmax;
    unsigned* Mkey = (unsigned*)sc;      // sc[0]
    float* Sp      = sc + 1;
    float* meanP   = sc + 16;
    float* meanT   = sc + 144;
    float* prefix  = sc + 272;
    float* h2g     = sc + 400;

    const int* pre_src  = pre;          const int* pre_dst  = pre + E;
    const int* post_src = post;         const int* post_dst = post + E;

    int gP = (P + 63)/64, gT = (T + 63)/64;

    k_init_small<<<1, 128, 0, stream>>>(pe, plen, W_pr, b_pr, prefix, meanP, meanT);
    k_embed_place<<<(P*32 + 255)/256, 256, 0, stream>>>(pf, W_pe, b_pe, place_h, P);
    k_embed_trans<<<(T*32 + 255)/256, 256, 0, stream>>>(tf, W_te, b_te, trans_h, T);

    for (int l = 0; l < L; l++){
        const float* p2tW = p2t_W + (size_t)l*H*H;   const float* p2tb = p2t_b + (size_t)l*H;
        const float* t2pW = t2p_W + (size_t)l*H*H;   const float* t2pb = t2p_b + (size_t)l*H;
        const float* puW  = pu_W  + (size_t)l*2*H*H; const float* pub  = pu_b  + (size_t)l*H;
        const float* tuW  = tu_W  + (size_t)l*2*H*H; const float* tub  = tu_b  + (size_t)l*H;
        const float* paW  = pa_W + (size_t)l*H;      const float* pab  = pa_b + l;
        const float* taW  = ta_W + (size_t)l*H;      const float* tab  = ta_b + l;

        // place -> transition
        k_gemm<<<gP, 256, 0, stream>>>(place_h, nullptr, p2tW, p2tb, nullptr, Xb, P, H, 0, Mkey);
        k_score<<<512, 256, 0, stream>>>(Xb, taW, tab, yb, P, Mkey);
        k_sumexp_zero<<<1024, 256, 0, stream>>>(pre_src, E, yb, Mkey, Sp, (float4*)Mb, (int)(fT/4));
        k_scatter<<<2048, 256, 0, stream>>>(pre_src, pre_dst, E, yb, Xb, Mb, Mkey, Sp);

        // transition -> place message transform (from OLD trans_h) + its scores
        k_gemm<<<gT, 256, 0, stream>>>(trans_h, nullptr, t2pW, t2pb, nullptr, Xb, T, H, 0, Mkey);
        k_score<<<512, 256, 0, stream>>>(Xb, paW, pab, yb, T, Mkey);

        // transition update (consumes Mb = trans_msg)
        k_gemm<<<gT, 256, 0, stream>>>(trans_h, Mb, tuW, tub, trans_h, trans_h, T, 2*H, 1, nullptr);

        // softmax denom + zero Mb (now free), then scatter place messages
        k_sumexp_zero<<<1024, 256, 0, stream>>>(post_src, E, yb, Mkey, Sp, (float4*)Mb, (int)(fP/4));
        k_scatter<<<2048, 256, 0, stream>>>(post_src, post_dst, E, yb, Xb, Mb, Mkey, Sp);

        // place update
        k_gemm<<<gP, 256, 0, stream>>>(place_h, Mb, puW, pub, place_h, place_h, P, 2*H, 1, nullptr);
    }

    k_colmean<<<256, 256, 0, stream>>>(place_h, P, meanP);
    k_colmean<<<256, 256, 0, stream>>>(trans_h, T, meanT);
    k_head<<<1, 256, 0, stream>>>(meanP, meanT, 1.f/(float)P, 1.f/(float)T,
                                  W_pp, b_pp, W_tp, b_tp, prefix, W1, b1, W2, b2, h2g);
    k_logits<<<(T + 255)/256, 256, 0, stream>>>(h2g, W3, b3, (float*)d_out, T);
}

// Round 2
// 1834.062 us; speedup vs baseline: 1.3381x; 1.3381x over previous
//
#include <hip/hip_runtime.h>
#include <cstddef>

#define H 128

// ---------------- helpers ----------------
__device__ __forceinline__ unsigned fkey(float f){
    unsigned u = __float_as_uint(f);
    return (u & 0x80000000u) ? ~u : (u | 0x80000000u);
}
__device__ __forceinline__ float funkey(unsigned k){
    unsigned u = (k & 0x80000000u) ? (k ^ 0x80000000u) : ~k;
    return __uint_as_float(u);
}

// ---------------- embeddings ----------------
__global__ __launch_bounds__(256) void k_embed_place(
    const float* __restrict__ pf, const float* __restrict__ Wpe,
    const float* __restrict__ bpe, float* __restrict__ out, int P)
{
    int idx = blockIdx.x*256 + threadIdx.x;     // float4 index over P*32
    if (idx >= P*32) return;
    int p = idx >> 5, q = (idx & 31) << 2;
    float v = pf[p];
    float4 w = *(const float4*)(Wpe + q);
    float4 b = *(const float4*)(bpe + q);
    float4 o;
    o.x = v*w.x + b.x; o.y = v*w.y + b.y; o.z = v*w.z + b.z; o.w = v*w.w + b.w;
    *(float4*)(out + (size_t)p*H + q) = o;
}

__global__ __launch_bounds__(256) void k_embed_trans(
    const float* __restrict__ tf, const float* __restrict__ Wte,
    const float* __restrict__ bte, float* __restrict__ out, int T)
{
    __shared__ float Wl[8*H];
    __shared__ float Bl[H];
    int tid = threadIdx.x;
    #pragma unroll
    for (int t = 0; t < 4; t++) Wl[tid + t*256] = Wte[tid + t*256];
    if (tid < H) Bl[tid] = bte[tid];
    __syncthreads();
    int idx = blockIdx.x*256 + tid;
    if (idx >= T*32) return;
    int t = idx >> 5, q = (idx & 31) << 2;
    float4 acc = *(float4*)(&Bl[q]);
    #pragma unroll
    for (int k = 0; k < 8; k++){
        float s = tf[(size_t)t*8 + k];
        float4 w = *(float4*)(&Wl[k*H + q]);
        acc.x += s*w.x; acc.y += s*w.y; acc.z += s*w.z; acc.w += s*w.w;
    }
    *(float4*)(out + (size_t)t*H + q) = acc;
}

// prefix embedding + zero small accumulators + all softmax slots
__global__ void k_init_small(const float* __restrict__ pe, int plen,
                             const float* __restrict__ Wpr, const float* __restrict__ bpr,
                             float* __restrict__ prefix, float* __restrict__ meanP,
                             float* __restrict__ meanT, float* __restrict__ slots)
{
    int c = threadIdx.x;  // 128 threads
    float a = bpr[c];
    for (int k = 0; k < plen; k++) a += pe[k]*Wpr[k*H + c];
    prefix[c] = a;
    meanP[c] = 0.f;
    meanT[c] = 0.f;
    if (c < 16) slots[c] = 0.f;   // 6 (Mkey,Sp) pairs + pad; fkey-space 0 == -inf
}

// ---------------- CSR build ----------------
__global__ __launch_bounds__(256) void k_zero_ints(int* __restrict__ p, int n)
{
    int i = blockIdx.x*256 + threadIdx.x;
    int stride = gridDim.x*256;
    for (; i < n; i += stride) p[i] = 0;
}

__global__ __launch_bounds__(256) void k_hist(
    const int* __restrict__ src, const int* __restrict__ dst, int E,
    int* __restrict__ deg, int* __restrict__ cnt)
{
    int i = blockIdx.x*256 + threadIdx.x;
    int stride = gridDim.x*256;
    for (; i < E; i += stride){
        atomicAdd(&deg[src[i]], 1);
        atomicAdd(&cnt[dst[i]], 1);
    }
}

// exclusive scan of cnt[0..N) -> rp[0..N], rp[N]=total; zeroes cnt for reuse as cursor
__global__ __launch_bounds__(1024) void k_scan(
    int* __restrict__ cnt, int N, int* __restrict__ rp)
{
    __shared__ int wsum[17];
    int tid = threadIdx.x;
    int lane = tid & 63, w = tid >> 6;
    int carry = 0;
    for (int base = 0; base < N; base += 1024){
        int i = base + tid;
        int v = (i < N) ? cnt[i] : 0;
        int s = v;
        #pragma unroll
        for (int o = 1; o < 64; o <<= 1){
            int u = __shfl_up(s, o);
            if (lane >= o) s += u;
        }
        if (lane == 63) wsum[w] = s;
        __syncthreads();
        if (tid == 0){
            int r = 0;
            #pragma unroll
            for (int k = 0; k < 16; k++){ int t = wsum[k]; wsum[k] = r; r += t; }
            wsum[16] = r;
        }
        __syncthreads();
        if (i < N){ rp[i] = carry + wsum[w] + s - v; cnt[i] = 0; }
        carry += wsum[16];
        __syncthreads();
    }
    if (tid == 0) rp[N] = carry;
}

__global__ __launch_bounds__(256) void k_fill(
    const int* __restrict__ src, const int* __restrict__ dst, int E,
    const int* __restrict__ rp, int* __restrict__ cur, int* __restrict__ csr)
{
    int i = blockIdx.x*256 + threadIdx.x;
    int stride = gridDim.x*256;
    for (; i < E; i += stride){
        int d = dst[i];
        int pos = rp[d] + atomicAdd(&cur[d], 1);
        csr[pos] = src[i];
    }
}

// ---------------- generic fused GEMM (+ optional fused attention score) -------
// out[M,128] = maybe_relu( maybe(resid) + [A1 | A2] @ W + bias )
// if aw != nullptr: y[r] = dot(out[r,:], aw) + ab ; atomicMax node max into Mkey
__global__ __launch_bounds__(256) void k_gemm(
    const float* __restrict__ A1, const float* __restrict__ A2,
    const float* __restrict__ W, const float* __restrict__ bias,
    const float* __restrict__ resid, float* __restrict__ out,
    int M, int K, int relu,
    const float* __restrict__ aw, const float* __restrict__ abp,
    float* __restrict__ y, unsigned* __restrict__ Mkey)
{
    __shared__ float As[64*36];     // +4 pad breaks bank conflicts
    __shared__ float Ws[32*H];
    __shared__ float awl[H];
    __shared__ float smax[16];
    int tid = threadIdx.x;
    if (aw && tid < H) awl[tid] = aw[tid];
    int row0 = blockIdx.x * 64;
    int tc = tid & 15, tr = tid >> 4;
    float acc[4][8];
    #pragma unroll
    for (int i = 0; i < 4; i++)
        #pragma unroll
        for (int j = 0; j < 8; j++) acc[i][j] = 0.f;

    for (int k0 = 0; k0 < K; k0 += 32){
        const float* Asrc = (k0 < H) ? A1 : A2;
        int kl = k0 & (H-1);
        #pragma unroll
        for (int t = 0; t < 2; t++){
            int f = tid + t*256;
            int r = f >> 3, kq = (f & 7) << 2;
            int rg = row0 + r;
            float4 v = make_float4(0.f, 0.f, 0.f, 0.f);
            if (rg < M) v = *(const float4*)(Asrc + (size_t)rg*H + kl + kq);
            *(float4*)(&As[r*36 + kq]) = v;
        }
        #pragma unroll
        for (int t = 0; t < 4; t++){
            int f = tid + t*256;
            int k = f >> 5, cq = (f & 31) << 2;
            *(float4*)(&Ws[k*H + cq]) = *(const float4*)(W + (size_t)(k0 + k)*H + cq);
        }
        __syncthreads();
        #pragma unroll
        for (int k = 0; k < 32; k++){
            float av[4];
            #pragma unroll
            for (int i = 0; i < 4; i++) av[i] = As[(tr*4 + i)*36 + k];
            float4 w0 = *(float4*)(&Ws[k*H + tc*4]);
            float4 w1 = *(float4*)(&Ws[k*H + 64 + tc*4]);
            #pragma unroll
            for (int i = 0; i < 4; i++){
                acc[i][0] += av[i]*w0.x; acc[i][1] += av[i]*w0.y;
                acc[i][2] += av[i]*w0.z; acc[i][3] += av[i]*w0.w;
                acc[i][4] += av[i]*w1.x; acc[i][5] += av[i]*w1.y;
                acc[i][6] += av[i]*w1.z; acc[i][7] += av[i]*w1.w;
            }
        }
        __syncthreads();
    }
    float p[4] = {0.f, 0.f, 0.f, 0.f};
    #pragma unroll
    for (int i = 0; i < 4; i++){
        int rg = row0 + tr*4 + i;
        if (rg >= M) continue;
        #pragma unroll
        for (int hh = 0; hh < 2; hh++){
            int c = hh*64 + tc*4;
            float4 v;
            v.x = acc[i][hh*4+0] + bias[c+0];
            v.y = acc[i][hh*4+1] + bias[c+1];
            v.z = acc[i][hh*4+2] + bias[c+2];
            v.w = acc[i][hh*4+3] + bias[c+3];
            if (resid){
                float4 rv = *(const float4*)(resid + (size_t)rg*H + c);
                v.x += rv.x; v.y += rv.y; v.z += rv.z; v.w += rv.w;
            }
            if (relu){
                v.x = fmaxf(v.x, 0.f); v.y = fmaxf(v.y, 0.f);
                v.z = fmaxf(v.z, 0.f); v.w = fmaxf(v.w, 0.f);
            }
            if (aw){
                p[i] += v.x*awl[c+0] + v.y*awl[c+1] + v.z*awl[c+2] + v.w*awl[c+3];
            }
            *(float4*)(out + (size_t)rg*H + c) = v;
        }
    }
    if (aw){
        #pragma unroll
        for (int i = 0; i < 4; i++){
            #pragma unroll
            for (int o = 1; o < 16; o <<= 1) p[i] += __shfl_xor(p[i], o);
        }
        if (tc == 0){
            float ab = abp[0];
            float lm = -3.402823466e38f;
            #pragma unroll
            for (int i = 0; i < 4; i++){
                int rg = row0 + tr*4 + i;
                if (rg < M){
                    float s = p[i] + ab;
                    y[rg] = s;
                    lm = fmaxf(lm, s);
                }
            }
            smax[tid >> 4] = lm;
        }
        __syncthreads();
        if (tid == 0){
            float m = smax[0];
            #pragma unroll
            for (int k = 1; k < 16; k++) m = fmaxf(m, smax[k]);
            atomicMax(Mkey, fkey(m));
        }
    }
}

// ---------------- softmax denominator: sum over nodes of deg * exp(y - M) -----
__global__ __launch_bounds__(256) void k_denom(
    const int* __restrict__ deg, int N, const float* __restrict__ y,
    const unsigned* __restrict__ Mkey, float* __restrict__ Sp)
{
    __shared__ float red[256];
    int tid = threadIdx.x;
    int gid = blockIdx.x*256 + tid, stride = gridDim.x*256;
    float Mv = funkey(Mkey[0]);
    float ls = 0.f;
    for (int n = gid; n < N; n += stride){
        int d = deg[n];
        if (d) ls += (float)d * expf(y[n] - Mv);
    }
    red[tid] = ls;
    __syncthreads();
    for (int s = 128; s > 0; s >>= 1){
        if (tid < s) red[tid] += red[tid + s];
        __syncthreads();
    }
    if (tid == 0) atomicAdd(Sp, red[0]);
}

// ---------------- CSR gather: Mb[r] = sum_{j in row r} softmax(e_j) * X[src_j]
__global__ __launch_bounds__(256) void k_gather(
    const int* __restrict__ rp, const int* __restrict__ csr, int Nrow,
    const float* __restrict__ y, const float* __restrict__ X,
    float* __restrict__ Mb, const unsigned* __restrict__ Mkey,
    const float* __restrict__ Sp)
{
    int lane = threadIdx.x & 63, w = threadIdx.x >> 6;
    int r = blockIdx.x*4 + w;                 // one wave per dst row
    if (r >= Nrow) return;
    float Mv = funkey(Mkey[0]);
    float invS = 1.f / Sp[0];
    int j0 = rp[r], j1 = rp[r+1];
    const float2* X2 = (const float2*)X;      // row stride 64 float2
    float2 a = make_float2(0.f, 0.f);
    for (int j = j0; j < j1; j++){
        int s = csr[j];                        // uniform across wave (broadcast)
        float wg = expf(y[s] - Mv) * invS;
        float2 xv = X2[(size_t)s*64 + lane];
        a.x += wg * xv.x;
        a.y += wg * xv.y;
    }
    ((float2*)Mb)[(size_t)r*64 + lane] = a;
}

// ---------------- column mean accumulator (pooling is linear) ----------------
__global__ __launch_bounds__(256) void k_colmean(
    const float* __restrict__ h, int N, float* __restrict__ accum)
{
    __shared__ float cs[256];
    int tid = threadIdx.x;
    int c = tid & 127, rr = tid >> 7;
    float a = 0.f;
    for (int r = blockIdx.x*2 + rr; r < N; r += gridDim.x*2)
        a += h[(size_t)r*H + c];
    cs[tid] = a;
    __syncthreads();
    if (tid < 128) atomicAdd(&accum[c], cs[tid] + cs[tid + 128]);
}

// ---------------- tiny MLP head ----------------
__global__ __launch_bounds__(256) void k_head(
    const float* __restrict__ meanP, const float* __restrict__ meanT,
    float invP, float invT,
    const float* __restrict__ Wpp, const float* __restrict__ bpp,
    const float* __restrict__ Wtp, const float* __restrict__ btp,
    const float* __restrict__ prefix,
    const float* __restrict__ W1, const float* __restrict__ b1,
    const float* __restrict__ W2, const float* __restrict__ b2,
    float* __restrict__ h2g)
{
    __shared__ float comb[384];
    __shared__ float h1s[256];
    int tid = threadIdx.x;
    if (tid < 128){
        float a = bpp[tid];
        for (int k = 0; k < 128; k++) a += meanP[k]*invP*Wpp[k*H + tid];
        comb[tid] = a;
        comb[256 + tid] = prefix[tid];
    } else {
        int c = tid - 128;
        float a = btp[c];
        for (int k = 0; k < 128; k++) a += meanT[k]*invT*Wtp[k*H + c];
        comb[128 + c] = a;
    }
    __syncthreads();
    {
        float a = b1[tid];
        for (int k = 0; k < 384; k++) a += comb[k]*W1[k*256 + tid];
        h1s[tid] = fmaxf(a, 0.f);
    }
    __syncthreads();
    if (tid < 128){
        float a = b2[tid];
        for (int k = 0; k < 256; k++) a += h1s[k]*W2[k*H + tid];
        h2g[tid] = fmaxf(a, 0.f);
    }
}

// ---------------- logits + sigmoid ----------------
__global__ __launch_bounds__(256) void k_logits(
    const float* __restrict__ h2g, const float* __restrict__ W3,
    const float* __restrict__ b3, float* __restrict__ out, int T)
{
    __shared__ float h2l[128];
    int tid = threadIdx.x;
    if (tid < 128) h2l[tid] = h2g[tid];
    __syncthreads();
    int t = blockIdx.x*256 + tid;
    if (t >= T) return;
    float a = b3[t];
    #pragma unroll 8
    for (int k = 0; k < 128; k++) a += h2l[k]*W3[(size_t)k*T + t];
    out[t] = 1.f/(1.f + expf(-a));
}

// ---------------- launch ----------------
extern "C" void kernel_launch(void* const* d_in, const int* in_sizes, int n_in,
                              void* d_out, int out_size, void* d_ws, size_t ws_size,
                              hipStream_t stream)
{
    (void)n_in; (void)out_size; (void)ws_size;
    const float* pf    = (const float*)d_in[0];
    const float* tf    = (const float*)d_in[1];
    const float* pe    = (const float*)d_in[2];
    const int*   pre   = (const int*)d_in[3];
    const int*   post  = (const int*)d_in[4];
    const float* W_pe  = (const float*)d_in[5];
    const float* b_pe  = (const float*)d_in[6];
    const float* W_te  = (const float*)d_in[7];
    const float* b_te  = (const float*)d_in[8];
    const float* W_pr  = (const float*)d_in[9];
    const float* b_pr  = (const float*)d_in[10];
    const float* p2t_W = (const float*)d_in[11];
    const float* p2t_b = (const float*)d_in[12];
    const float* t2p_W = (const float*)d_in[13];
    const float* t2p_b = (const float*)d_in[14];
    const float* pu_W  = (const float*)d_in[15];
    const float* pu_b  = (const float*)d_in[16];
    const float* tu_W  = (const float*)d_in[17];
    const float* tu_b  = (const float*)d_in[18];
    const float* pa_W  = (const float*)d_in[19];
    const float* pa_b  = (const float*)d_in[20];
    const float* ta_W  = (const float*)d_in[21];
    const float* ta_b  = (const float*)d_in[22];
    const float* W_pp  = (const float*)d_in[23];
    const float* b_pp  = (const float*)d_in[24];
    const float* W_tp  = (const float*)d_in[25];
    const float* b_tp  = (const float*)d_in[26];
    const float* W1    = (const float*)d_in[27];
    const float* b1    = (const float*)d_in[28];
    const float* W2    = (const float*)d_in[29];
    const float* b2    = (const float*)d_in[30];
    const float* W3    = (const float*)d_in[31];
    const float* b3    = (const float*)d_in[32];

    int P = in_sizes[0];
    int T = in_sizes[1] / 8;
    int E = in_sizes[3] / 2;
    int plen = in_sizes[2];
    int L = in_sizes[11] / (H*H);

    float* ws = (float*)d_ws;
    size_t fP = (size_t)P*H, fT = (size_t)T*H;
    size_t fN = (fP > fT) ? fP : fT;
    int   Nmax = (P > T) ? P : T;
    float* place_h = ws;
    float* trans_h = place_h + fP;
    float* Xb      = trans_h + fT;
    float* Mb      = Xb + fN;
    float* yb      = Mb + fN;
    float* sc      = yb + Nmax;
    // sc[0..15]: 6 (Mkey,Sp) pairs (+pad); then small vectors
    float* meanP   = sc + 16;
    float* meanT   = sc + 144;
    float* prefix  = sc + 272;
    float* h2g     = sc + 400;
    int*   iw      = (int*)(sc + 544);
    int* cntPre  = iw;                 // [T] cursor / dst-hist of pre
    int* degPre  = cntPre + T;         // [P] src-hist of pre (places)
    int* cntPost = degPre + P;         // [P] cursor / dst-hist of post
    int* degPost = cntPost + P;        // [T] src-hist of post (transitions)
    int* rpPre   = degPost + T;        // [T+1]
    int* rpPost  = rpPre + (T + 1);    // [P+1]
    int* csrPre  = rpPost + (P + 2);   // [E]
    int* csrPost = csrPre + E;         // [E]

    const int* pre_src  = pre;          const int* pre_dst  = pre + E;
    const int* post_src = post;         const int* post_dst = post + E;

    int gP = (P + 63)/64, gT = (T + 63)/64;

    k_init_small<<<1, 128, 0, stream>>>(pe, plen, W_pr, b_pr, prefix, meanP, meanT, sc);
    k_zero_ints<<<512, 256, 0, stream>>>(iw, 2*(P + T));
    k_hist<<<1024, 256, 0, stream>>>(pre_src, pre_dst, E, degPre, cntPre);
    k_hist<<<1024, 256, 0, stream>>>(post_src, post_dst, E, degPost, cntPost);
    k_scan<<<1, 1024, 0, stream>>>(cntPre, T, rpPre);
    k_scan<<<1, 1024, 0, stream>>>(cntPost, P, rpPost);
    k_fill<<<1024, 256, 0, stream>>>(pre_src, pre_dst, E, rpPre, cntPre, csrPre);
    k_fill<<<1024, 256, 0, stream>>>(post_src, post_dst, E, rpPost, cntPost, csrPost);

    k_embed_place<<<(P*32 + 255)/256, 256, 0, stream>>>(pf, W_pe, b_pe, place_h, P);
    k_embed_trans<<<(T*32 + 255)/256, 256, 0, stream>>>(tf, W_te, b_te, trans_h, T);

    for (int l = 0; l < L; l++){
        const float* p2tW = p2t_W + (size_t)l*H*H;   const float* p2tb = p2t_b + (size_t)l*H;
        const float* t2pW = t2p_W + (size_t)l*H*H;   const float* t2pb = t2p_b + (size_t)l*H;
        const float* puW  = pu_W  + (size_t)l*2*H*H; const float* pub  = pu_b  + (size_t)l*H;
        const float* tuW  = tu_W  + (size_t)l*2*H*H; const float* tub  = tu_b  + (size_t)l*H;
        const float* paW  = pa_W + (size_t)l*H;      const float* pab  = pa_b + l;
        const float* taW  = ta_W + (size_t)l*H;      const float* tab  = ta_b + l;
        unsigned* MkA = (unsigned*)(sc + l*4 + 0);   float* SpA = sc + l*4 + 1;
        unsigned* MkB = (unsigned*)(sc + l*4 + 2);   float* SpB = sc + l*4 + 3;

        // phase A: place -> transition (scores over place nodes, fused in GEMM)
        k_gemm<<<gP, 256, 0, stream>>>(place_h, nullptr, p2tW, p2tb, nullptr, Xb,
                                       P, H, 0, taW, tab, yb, MkA);
        k_denom<<<128, 256, 0, stream>>>(degPre, P, yb, MkA, SpA);
        k_gather<<<(T + 3)/4, 256, 0, stream>>>(rpPre, csrPre, T, yb, Xb, Mb, MkA, SpA);

        // phase B message transform from OLD trans_h (+ its scores)
        k_gemm<<<gT, 256, 0, stream>>>(trans_h, nullptr, t2pW, t2pb, nullptr, Xb,
                                       T, H, 0, paW, pab, yb, MkB);
        k_denom<<<128, 256, 0, stream>>>(degPost, T, yb, MkB, SpB);

        // transition update (consumes Mb = trans_msg)
        k_gemm<<<gT, 256, 0, stream>>>(trans_h, Mb, tuW, tub, trans_h, trans_h,
                                       T, 2*H, 1, nullptr, nullptr, nullptr, nullptr);

        // place messages
        k_gather<<<(P + 3)/4, 256, 0, stream>>>(rpPost, csrPost, P, yb, Xb, Mb, MkB, SpB);

        // place update
        k_gemm<<<gP, 256, 0, stream>>>(place_h, Mb, puW, pub, place_h, place_h,
                                       P, 2*H, 1, nullptr, nullptr, nullptr, nullptr);
    }

    k_colmean<<<256, 256, 0, stream>>>(place_h, P, meanP);
    k_colmean<<<256, 256, 0, stream>>>(trans_h, T, meanT);
    k_head<<<1, 256, 0, stream>>>(meanP, meanT, 1.f/(float)P, 1.f/(float)T,
                                  W_pp, b_pp, W_tp, b_tp, prefix, W1, b1, W2, b2, h2g);
    k_logits<<<(T + 255)/256, 256, 0, stream>>>(h2g, W3, b3, (float*)d_out, T);
}

// Round 3
// 1526.203 us; speedup vs baseline: 1.6080x; 1.2017x over previous
//
#include <hip/hip_runtime.h>
#include <cstddef>

#define H 128

typedef unsigned short ushort_t;
typedef __attribute__((ext_vector_type(8))) short short8;
typedef __attribute__((ext_vector_type(4))) float floatx4;

// ---------------- helpers ----------------
__device__ __forceinline__ unsigned fkey(float f){
    unsigned u = __float_as_uint(f);
    return (u & 0x80000000u) ? ~u : (u | 0x80000000u);
}
__device__ __forceinline__ float funkey(unsigned k){
    unsigned u = (k & 0x80000000u) ? (k ^ 0x80000000u) : ~k;
    return __uint_as_float(u);
}
__device__ __forceinline__ ushort_t f2bf(float f){
    unsigned u = __float_as_uint(f);
    u += 0x7fffu + ((u >> 16) & 1u);      // round-to-nearest-even
    return (ushort_t)(u >> 16);
}
__device__ __forceinline__ float bf2f(ushort_t h){
    return __uint_as_float(((unsigned)h) << 16);
}

// ---------------- embeddings (write bf16 states) ----------------
__global__ __launch_bounds__(256) void k_embed_place(
    const float* __restrict__ pf, const float* __restrict__ Wpe,
    const float* __restrict__ bpe, ushort_t* __restrict__ out, int P)
{
    int idx = blockIdx.x*256 + threadIdx.x;     // 4-elem group index over P*32
    if (idx >= P*32) return;
    int p = idx >> 5, q = (idx & 31) << 2;
    float v = pf[p];
    float4 w = *(const float4*)(Wpe + q);
    float4 b = *(const float4*)(bpe + q);
    ushort4 o;
    o.x = f2bf(v*w.x + b.x); o.y = f2bf(v*w.y + b.y);
    o.z = f2bf(v*w.z + b.z); o.w = f2bf(v*w.w + b.w);
    *(ushort4*)(out + (size_t)p*H + q) = o;
}

__global__ __launch_bounds__(256) void k_embed_trans(
    const float* __restrict__ tf, const float* __restrict__ Wte,
    const float* __restrict__ bte, ushort_t* __restrict__ out, int T)
{
    __shared__ float Wl[8*H];
    __shared__ float Bl[H];
    int tid = threadIdx.x;
    #pragma unroll
    for (int t = 0; t < 4; t++) Wl[tid + t*256] = Wte[tid + t*256];
    if (tid < H) Bl[tid] = bte[tid];
    __syncthreads();
    int idx = blockIdx.x*256 + tid;
    if (idx >= T*32) return;
    int t = idx >> 5, q = (idx & 31) << 2;
    float4 acc = *(float4*)(&Bl[q]);
    #pragma unroll
    for (int k = 0; k < 8; k++){
        float s = tf[(size_t)t*8 + k];
        float4 w = *(float4*)(&Wl[k*H + q]);
        acc.x += s*w.x; acc.y += s*w.y; acc.z += s*w.z; acc.w += s*w.w;
    }
    ushort4 o;
    o.x = f2bf(acc.x); o.y = f2bf(acc.y); o.z = f2bf(acc.z); o.w = f2bf(acc.w);
    *(ushort4*)(out + (size_t)t*H + q) = o;
}

// prefix embedding + zero small accumulators + all softmax slots
__global__ void k_init_small(const float* __restrict__ pe, int plen,
                             const float* __restrict__ Wpr, const float* __restrict__ bpr,
                             float* __restrict__ prefix, float* __restrict__ meanP,
                             float* __restrict__ meanT, float* __restrict__ slots)
{
    int c = threadIdx.x;  // 128 threads
    float a = bpr[c];
    for (int k = 0; k < plen; k++) a += pe[k]*Wpr[k*H + c];
    prefix[c] = a;
    meanP[c] = 0.f;
    meanT[c] = 0.f;
    if (c < 16) slots[c] = 0.f;   // fkey-space 0 == -inf
}

// ---------------- weight transpose + bf16 convert ----------------
// per layer l: WT layout [p2tT 128x128][t2pT 128x128][tuT 128x256][puT 128x256]
__global__ __launch_bounds__(256) void k_wconv(
    const float* __restrict__ p2t_W, const float* __restrict__ t2p_W,
    const float* __restrict__ tu_W,  const float* __restrict__ pu_W,
    ushort_t* __restrict__ WT, int total)
{
    int e = blockIdx.x*256 + threadIdx.x;
    if (e >= total) return;
    int l = e / 98304, o = e - l*98304;
    const float* src; int K, oo;
    if (o < 16384)      { src = p2t_W + (size_t)l*16384; K = 128; oo = o; }
    else if (o < 32768) { src = t2p_W + (size_t)l*16384; K = 128; oo = o - 16384; }
    else if (o < 65536) { src = tu_W  + (size_t)l*32768; K = 256; oo = o - 32768; }
    else                { src = pu_W  + (size_t)l*32768; K = 256; oo = o - 65536; }
    int n = oo / K, k = oo - n*K;
    WT[e] = f2bf(src[(size_t)k*H + n]);
}

// ---------------- CSR build ----------------
__global__ __launch_bounds__(256) void k_zero_ints(int* __restrict__ p, int n)
{
    int i = blockIdx.x*256 + threadIdx.x;
    int stride = gridDim.x*256;
    for (; i < n; i += stride) p[i] = 0;
}

__global__ __launch_bounds__(256) void k_hist(
    const int* __restrict__ src, const int* __restrict__ dst, int E,
    int* __restrict__ deg, int* __restrict__ cnt)
{
    int i = blockIdx.x*256 + threadIdx.x;
    int stride = gridDim.x*256;
    for (; i < E; i += stride){
        atomicAdd(&deg[src[i]], 1);
        atomicAdd(&cnt[dst[i]], 1);
    }
}

__global__ __launch_bounds__(1024) void k_scan(
    int* __restrict__ cnt, int N, int* __restrict__ rp)
{
    __shared__ int wsum[17];
    int tid = threadIdx.x;
    int lane = tid & 63, w = tid >> 6;
    int carry = 0;
    for (int base = 0; base < N; base += 1024){
        int i = base + tid;
        int v = (i < N) ? cnt[i] : 0;
        int s = v;
        #pragma unroll
        for (int o = 1; o < 64; o <<= 1){
            int u = __shfl_up(s, o);
            if (lane >= o) s += u;
        }
        if (lane == 63) wsum[w] = s;
        __syncthreads();
        if (tid == 0){
            int r = 0;
            #pragma unroll
            for (int k = 0; k < 16; k++){ int t = wsum[k]; wsum[k] = r; r += t; }
            wsum[16] = r;
        }
        __syncthreads();
        if (i < N){ rp[i] = carry + wsum[w] + s - v; cnt[i] = 0; }
        carry += wsum[16];
        __syncthreads();
    }
    if (tid == 0) rp[N] = carry;
}

__global__ __launch_bounds__(256) void k_fill(
    const int* __restrict__ src, const int* __restrict__ dst, int E,
    const int* __restrict__ rp, int* __restrict__ cur, int* __restrict__ csr)
{
    int i = blockIdx.x*256 + threadIdx.x;
    int stride = gridDim.x*256;
    for (; i < E; i += stride){
        int d = dst[i];
        int pos = rp[d] + atomicAdd(&cur[d], 1);
        csr[pos] = src[i];
    }
}

// ---------------- bf16 MFMA GEMM (+ fused epilogue) ----------------
// out[M,128](bf16) = maybe_relu( maybe(resid) + [A1|A2] @ W + bias )
// W passed as WT[n][k] (bf16). Fused score: y[r] = dot(out[r,:], aw)+ab; max->Mkey
// 128x128 tile, BK=32, 256 threads = 4 waves in 2x2 quadrants, 4x4 mfma tiles/wave.
__global__ __launch_bounds__(256) void k_gemm_bf(
    const ushort_t* __restrict__ A1, const ushort_t* __restrict__ A2,
    const ushort_t* __restrict__ WT, const float* __restrict__ bias,
    const ushort_t* __restrict__ resid, ushort_t* __restrict__ out,
    int M, int K, int relu,
    const float* __restrict__ aw, const float* __restrict__ abp,
    float* __restrict__ y, unsigned* __restrict__ Mkey)
{
    __shared__ ushort_t As[128*40];   // [row][k] stride 40 (80B rows: 16B-aligned, 2-way banks)
    __shared__ ushort_t Bs[128*40];   // [n][k]
    __shared__ float bl[H];
    __shared__ float awl[H];
    __shared__ float ybuf[H];
    int tid = threadIdx.x;
    int lane = tid & 63, wid = tid >> 6;
    int wm = wid & 1, wn = wid >> 1;
    int quad = lane >> 4, l15 = lane & 15;
    int row0 = blockIdx.x * 128;

    if (tid < H){
        bl[tid] = bias[tid];
        if (aw){ awl[tid] = aw[tid]; ybuf[tid] = 0.f; }
    }

    floatx4 acc[4][4];
    #pragma unroll
    for (int i = 0; i < 4; i++)
        #pragma unroll
        for (int j = 0; j < 4; j++) acc[i][j] = (floatx4)0.f;

    int r = tid >> 2, c = (tid & 3) * 8;          // staging coords: 4 threads/row, 16B each
    for (int k0 = 0; k0 < K; k0 += 32){
        const ushort_t* Asrc; int kl;
        if (k0 < H){ Asrc = A1; kl = k0; } else { Asrc = A2; kl = k0 - H; }
        #pragma unroll
        for (int t = 0; t < 2; t++){
            int rr = r + t*64;
            int rg = row0 + rr;
            int4 v = make_int4(0,0,0,0);
            if (rg < M) v = *(const int4*)(Asrc + (size_t)rg*H + kl + c);
            *(int4*)(&As[rr*40 + c]) = v;
            *(int4*)(&Bs[rr*40 + c]) = *(const int4*)(WT + (size_t)rr*K + k0 + c);
        }
        __syncthreads();
        short8 a_frag[4], b_frag[4];
        #pragma unroll
        for (int i = 0; i < 4; i++)
            a_frag[i] = *(const short8*)(&As[(wm*64 + i*16 + l15)*40 + quad*8]);
        #pragma unroll
        for (int j = 0; j < 4; j++)
            b_frag[j] = *(const short8*)(&Bs[(wn*64 + j*16 + l15)*40 + quad*8]);
        #pragma unroll
        for (int i = 0; i < 4; i++)
            #pragma unroll
            for (int j = 0; j < 4; j++)
                acc[i][j] = __builtin_amdgcn_mfma_f32_16x16x32_bf16(
                                a_frag[i], b_frag[j], acc[i][j], 0, 0, 0);
        __syncthreads();
    }

    // epilogue: D[row][col], row = wm*64+i*16+quad*4+rr, col = wn*64+j*16+l15
    float pacc[4][4];
    #pragma unroll
    for (int i = 0; i < 4; i++)
        #pragma unroll
        for (int rr = 0; rr < 4; rr++) pacc[i][rr] = 0.f;

    #pragma unroll
    for (int i = 0; i < 4; i++){
        int mbase = wm*64 + i*16 + quad*4;
        #pragma unroll
        for (int j = 0; j < 4; j++){
            int col = wn*64 + j*16 + l15;
            float bcol = bl[col];
            #pragma unroll
            for (int rr = 0; rr < 4; rr++){
                int grow = row0 + mbase + rr;
                if (grow >= M) continue;
                float v = acc[i][j][rr] + bcol;
                if (resid) v += bf2f(resid[(size_t)grow*H + col]);
                if (relu)  v = fmaxf(v, 0.f);
                out[(size_t)grow*H + col] = f2bf(v);
                if (aw) pacc[i][rr] += v * awl[col];
            }
        }
    }
    if (aw){
        #pragma unroll
        for (int i = 0; i < 4; i++)
            #pragma unroll
            for (int rr = 0; rr < 4; rr++){
                float p = pacc[i][rr];
                #pragma unroll
                for (int o = 1; o < 16; o <<= 1) p += __shfl_xor(p, o);
                if (l15 == 0) atomicAdd(&ybuf[wm*64 + i*16 + quad*4 + rr], p);
            }
        __syncthreads();
        if (tid < H){
            int grow = row0 + tid;
            float s = -3.402823466e38f;
            if (grow < M){
                s = ybuf[tid] + abp[0];
                y[grow] = s;
            }
            float m = s;
            #pragma unroll
            for (int o = 1; o < 64; o <<= 1) m = fmaxf(m, __shfl_xor(m, o));
            if (lane == 0) atomicMax(Mkey, fkey(m));
        }
    }
}

// ---------------- softmax denominator: sum over nodes of deg * exp(y - M) -----
__global__ __launch_bounds__(256) void k_denom(
    const int* __restrict__ deg, int N, const float* __restrict__ y,
    const unsigned* __restrict__ Mkey, float* __restrict__ Sp)
{
    __shared__ float red[256];
    int tid = threadIdx.x;
    int gid = blockIdx.x*256 + tid, stride = gridDim.x*256;
    float Mv = funkey(Mkey[0]);
    float ls = 0.f;
    for (int n = gid; n < N; n += stride){
        int d = deg[n];
        if (d) ls += (float)d * expf(y[n] - Mv);
    }
    red[tid] = ls;
    __syncthreads();
    for (int s = 128; s > 0; s >>= 1){
        if (tid < s) red[tid] += red[tid + s];
        __syncthreads();
    }
    if (tid == 0) atomicAdd(Sp, red[0]);
}

// ---------------- CSR gather (bf16 X -> bf16 Mb) ----------------
__global__ __launch_bounds__(256) void k_gather(
    const int* __restrict__ rp, const int* __restrict__ csr, int Nrow,
    const float* __restrict__ y, const ushort_t* __restrict__ X,
    ushort_t* __restrict__ Mb, const unsigned* __restrict__ Mkey,
    const float* __restrict__ Sp)
{
    int lane = threadIdx.x & 63, w = threadIdx.x >> 6;
    int r = blockIdx.x*4 + w;                 // one wave per dst row
    if (r >= Nrow) return;
    float Mv = funkey(Mkey[0]);
    float invS = 1.f / Sp[0];
    int j0 = rp[r], j1 = rp[r+1];
    const unsigned* X2 = (const unsigned*)X;  // 2 bf16 per lane, row = 64 uints
    float ax = 0.f, ay = 0.f;
    for (int j = j0; j < j1; j++){
        int s = csr[j];                        // uniform across wave
        float wg = expf(y[s] - Mv) * invS;
        unsigned u = X2[(size_t)s*64 + lane];
        ax += wg * __uint_as_float(u << 16);
        ay += wg * __uint_as_float(u & 0xffff0000u);
    }
    unsigned o = ((unsigned)f2bf(ay) << 16) | (unsigned)f2bf(ax);
    ((unsigned*)Mb)[(size_t)r*64 + lane] = o;
}

// ---------------- column mean accumulator (bf16 input) ----------------
__global__ __launch_bounds__(256) void k_colmean(
    const ushort_t* __restrict__ h, int N, float* __restrict__ accum)
{
    __shared__ float cs[256];
    int tid = threadIdx.x;
    int c = tid & 127, rr = tid >> 7;
    float a = 0.f;
    for (int r = blockIdx.x*2 + rr; r < N; r += gridDim.x*2)
        a += bf2f(h[(size_t)r*H + c]);
    cs[tid] = a;
    __syncthreads();
    if (tid < 128) atomicAdd(&accum[c], cs[tid] + cs[tid + 128]);
}

// ---------------- tiny MLP head ----------------
__global__ __launch_bounds__(256) void k_head(
    const float* __restrict__ meanP, const float* __restrict__ meanT,
    float invP, float invT,
    const float* __restrict__ Wpp, const float* __restrict__ bpp,
    const float* __restrict__ Wtp, const float* __restrict__ btp,
    const float* __restrict__ prefix,
    const float* __restrict__ W1, const float* __restrict__ b1,
    const float* __restrict__ W2, const float* __restrict__ b2,
    float* __restrict__ h2g)
{
    __shared__ float comb[384];
    __shared__ float h1s[256];
    int tid = threadIdx.x;
    if (tid < 128){
        float a = bpp[tid];
        for (int k = 0; k < 128; k++) a += meanP[k]*invP*Wpp[k*H + tid];
        comb[tid] = a;
        comb[256 + tid] = prefix[tid];
    } else {
        int c = tid - 128;
        float a = btp[c];
        for (int k = 0; k < 128; k++) a += meanT[k]*invT*Wtp[k*H + c];
        comb[128 + c] = a;
    }
    __syncthreads();
    {
        float a = b1[tid];
        for (int k = 0; k < 384; k++) a += comb[k]*W1[k*256 + tid];
        h1s[tid] = fmaxf(a, 0.f);
    }
    __syncthreads();
    if (tid < 128){
        float a = b2[tid];
        for (int k = 0; k < 256; k++) a += h1s[k]*W2[k*H + tid];
        h2g[tid] = fmaxf(a, 0.f);
    }
}

// ---------------- logits + sigmoid ----------------
__global__ __launch_bounds__(256) void k_logits(
    const float* __restrict__ h2g, const float* __restrict__ W3,
    const float* __restrict__ b3, float* __restrict__ out, int T)
{
    __shared__ float h2l[128];
    int tid = threadIdx.x;
    if (tid < 128) h2l[tid] = h2g[tid];
    __syncthreads();
    int t = blockIdx.x*256 + tid;
    if (t >= T) return;
    float a = b3[t];
    #pragma unroll 8
    for (int k = 0; k < 128; k++) a += h2l[k]*W3[(size_t)k*T + t];
    out[t] = 1.f/(1.f + expf(-a));
}

// ---------------- launch ----------------
extern "C" void kernel_launch(void* const* d_in, const int* in_sizes, int n_in,
                              void* d_out, int out_size, void* d_ws, size_t ws_size,
                              hipStream_t stream)
{
    (void)n_in; (void)out_size; (void)ws_size;
    const float* pf    = (const float*)d_in[0];
    const float* tf    = (const float*)d_in[1];
    const float* pe    = (const float*)d_in[2];
    const int*   pre   = (const int*)d_in[3];
    const int*   post  = (const int*)d_in[4];
    const float* W_pe  = (const float*)d_in[5];
    const float* b_pe  = (const float*)d_in[6];
    const float* W_te  = (const float*)d_in[7];
    const float* b_te  = (const float*)d_in[8];
    const float* W_pr  = (const float*)d_in[9];
    const float* b_pr  = (const float*)d_in[10];
    const float* p2t_W = (const float*)d_in[11];
    const float* p2t_b = (const float*)d_in[12];
    const float* t2p_W = (const float*)d_in[13];
    const float* t2p_b = (const float*)d_in[14];
    const float* pu_W  = (const float*)d_in[15];
    const float* pu_b  = (const float*)d_in[16];
    const float* tu_W  = (const float*)d_in[17];
    const float* tu_b  = (const float*)d_in[18];
    const float* pa_W  = (const float*)d_in[19];
    const float* pa_b  = (const float*)d_in[20];
    const float* ta_W  = (const float*)d_in[21];
    const float* ta_b  = (const float*)d_in[22];
    const float* W_pp  = (const float*)d_in[23];
    const float* b_pp  = (const float*)d_in[24];
    const float* W_tp  = (const float*)d_in[25];
    const float* b_tp  = (const float*)d_in[26];
    const float* W1    = (const float*)d_in[27];
    const float* b1    = (const float*)d_in[28];
    const float* W2    = (const float*)d_in[29];
    const float* b2    = (const float*)d_in[30];
    const float* W3    = (const float*)d_in[31];
    const float* b3    = (const float*)d_in[32];

    int P = in_sizes[0];
    int T = in_sizes[1] / 8;
    int E = in_sizes[3] / 2;
    int plen = in_sizes[2];
    int L = in_sizes[11] / (H*H);

    float* ws = (float*)d_ws;
    size_t fP = (size_t)P*H, fT = (size_t)T*H;
    size_t fN = (fP > fT) ? fP : fT;
    int   Nmax = (P > T) ? P : T;

    float* yb = ws;                       // [Nmax] fp32 scores
    float* sc = yb + Nmax;                // 16 softmax slots + small vectors
    float* meanP   = sc + 16;
    float* meanT   = sc + 144;
    float* prefix  = sc + 272;
    float* h2g     = sc + 400;            // end at sc+544 (16B aligned)

    ushort_t* bh = (ushort_t*)(sc + 544);
    ushort_t* place_h = bh;               // [P,128] bf16
    ushort_t* trans_h = place_h + fP;     // [T,128]
    ushort_t* Xb      = trans_h + fT;     // [Nmax,128]
    ushort_t* Mb      = Xb + fN;          // [Nmax,128]
    ushort_t* WTb     = Mb + fN;          // L*98304 bf16 transposed weights

    int* iw = (int*)(WTb + (size_t)L*98304);
    int* cntPre  = iw;                 // [T]
    int* degPre  = cntPre + T;         // [P]
    int* cntPost = degPre + P;         // [P]
    int* degPost = cntPost + P;        // [T]
    int* rpPre   = degPost + T;        // [T+1]
    int* rpPost  = rpPre + (T + 1);    // [P+1]
    int* csrPre  = rpPost + (P + 2);   // [E]
    int* csrPost = csrPre + E;         // [E]

    const int* pre_src  = pre;          const int* pre_dst  = pre + E;
    const int* post_src = post;         const int* post_dst = post + E;

    int g128P = (P + 127)/128, g128T = (T + 127)/128;
    int wtot = L*98304;

    k_init_small<<<1, 128, 0, stream>>>(pe, plen, W_pr, b_pr, prefix, meanP, meanT, sc);
    k_wconv<<<(wtot + 255)/256, 256, 0, stream>>>(p2t_W, t2p_W, tu_W, pu_W, WTb, wtot);
    k_zero_ints<<<512, 256, 0, stream>>>(iw, 2*(P + T));
    k_hist<<<1024, 256, 0, stream>>>(pre_src, pre_dst, E, degPre, cntPre);
    k_hist<<<1024, 256, 0, stream>>>(post_src, post_dst, E, degPost, cntPost);
    k_scan<<<1, 1024, 0, stream>>>(cntPre, T, rpPre);
    k_scan<<<1, 1024, 0, stream>>>(cntPost, P, rpPost);
    k_fill<<<1024, 256, 0, stream>>>(pre_src, pre_dst, E, rpPre, cntPre, csrPre);
    k_fill<<<1024, 256, 0, stream>>>(post_src, post_dst, E, rpPost, cntPost, csrPost);

    k_embed_place<<<(P*32 + 255)/256, 256, 0, stream>>>(pf, W_pe, b_pe, place_h, P);
    k_embed_trans<<<(T*32 + 255)/256, 256, 0, stream>>>(tf, W_te, b_te, trans_h, T);

    for (int l = 0; l < L; l++){
        const ushort_t* WTl  = WTb + (size_t)l*98304;
        const ushort_t* p2tT = WTl;
        const ushort_t* t2pT = WTl + 16384;
        const ushort_t* tuT  = WTl + 32768;
        const ushort_t* puT  = WTl + 65536;
        const float* p2tb = p2t_b + (size_t)l*H;
        const float* t2pb = t2p_b + (size_t)l*H;
        const float* pub  = pu_b  + (size_t)l*H;
        const float* tub  = tu_b  + (size_t)l*H;
        const float* paW  = pa_W + (size_t)l*H;   const float* pab = pa_b + l;
        const float* taW  = ta_W + (size_t)l*H;   const float* tab = ta_b + l;
        unsigned* MkA = (unsigned*)(sc + l*4 + 0);   float* SpA = sc + l*4 + 1;
        unsigned* MkB = (unsigned*)(sc + l*4 + 2);   float* SpB = sc + l*4 + 3;

        // phase A: place -> transition (scores over place nodes fused)
        k_gemm_bf<<<g128P, 256, 0, stream>>>(place_h, nullptr, p2tT, p2tb, nullptr, Xb,
                                             P, H, 0, taW, tab, yb, MkA);
        k_denom<<<128, 256, 0, stream>>>(degPre, P, yb, MkA, SpA);
        k_gather<<<(T + 3)/4, 256, 0, stream>>>(rpPre, csrPre, T, yb, Xb, Mb, MkA, SpA);

        // phase B: transform from OLD trans_h (+ its scores)
        k_gemm_bf<<<g128T, 256, 0, stream>>>(trans_h, nullptr, t2pT, t2pb, nullptr, Xb,
                                             T, H, 0, paW, pab, yb, MkB);
        k_denom<<<128, 256, 0, stream>>>(degPost, T, yb, MkB, SpB);

        // transition update (consumes Mb = trans_msg), in-place
        k_gemm_bf<<<g128T, 256, 0, stream>>>(trans_h, Mb, tuT, tub, trans_h, trans_h,
                                             T, 2*H, 1, nullptr, nullptr, nullptr, nullptr);

        // place messages, then place update in-place
        k_gather<<<(P + 3)/4, 256, 0, stream>>>(rpPost, csrPost, P, yb, Xb, Mb, MkB, SpB);
        k_gemm_bf<<<g128P, 256, 0, stream>>>(place_h, Mb, puT, pub, place_h, place_h,
                                             P, 2*H, 1, nullptr, nullptr, nullptr, nullptr);
    }

    k_colmean<<<256, 256, 0, stream>>>(place_h, P, meanP);
    k_colmean<<<256, 256, 0, stream>>>(trans_h, T, meanT);
    k_head<<<1, 256, 0, stream>>>(meanP, meanT, 1.f/(float)P, 1.f/(float)T,
                                  W_pp, b_pp, W_tp, b_tp, prefix, W1, b1, W2, b2, h2g);
    k_logits<<<(T + 255)/256, 256, 0, stream>>>(h2g, W3, b3, (float*)d_out, T);
}

// Round 4
// 1364.294 us; speedup vs baseline: 1.7988x; 1.1187x over previous
//
#include <hip/hip_runtime.h>
#include <cstddef>

#define H 128

typedef unsigned short ushort_t;
typedef __attribute__((ext_vector_type(8))) short short8;
typedef __attribute__((ext_vector_type(4))) float floatx4;

// ---------------- helpers ----------------
__device__ __forceinline__ unsigned fkey(float f){
    unsigned u = __float_as_uint(f);
    return (u & 0x80000000u) ? ~u : (u | 0x80000000u);
}
__device__ __forceinline__ float funkey(unsigned k){
    unsigned u = (k & 0x80000000u) ? (k ^ 0x80000000u) : ~k;
    return __uint_as_float(u);
}
__device__ __forceinline__ ushort_t f2bf(float f){
    unsigned u = __float_as_uint(f);
    u += 0x7fffu + ((u >> 16) & 1u);      // round-to-nearest-even
    return (ushort_t)(u >> 16);
}
__device__ __forceinline__ float bf2f(ushort_t h){
    return __uint_as_float(((unsigned)h) << 16);
}

// ---------------- embeddings (write bf16 states) ----------------
__global__ __launch_bounds__(256) void k_embed_place(
    const float* __restrict__ pf, const float* __restrict__ Wpe,
    const float* __restrict__ bpe, ushort_t* __restrict__ out, int P)
{
    int idx = blockIdx.x*256 + threadIdx.x;     // 4-elem group index over P*32
    if (idx >= P*32) return;
    int p = idx >> 5, q = (idx & 31) << 2;
    float v = pf[p];
    float4 w = *(const float4*)(Wpe + q);
    float4 b = *(const float4*)(bpe + q);
    ushort4 o;
    o.x = f2bf(v*w.x + b.x); o.y = f2bf(v*w.y + b.y);
    o.z = f2bf(v*w.z + b.z); o.w = f2bf(v*w.w + b.w);
    *(ushort4*)(out + (size_t)p*H + q) = o;
}

__global__ __launch_bounds__(256) void k_embed_trans(
    const float* __restrict__ tf, const float* __restrict__ Wte,
    const float* __restrict__ bte, ushort_t* __restrict__ out, int T)
{
    __shared__ float Wl[8*H];
    __shared__ float Bl[H];
    int tid = threadIdx.x;
    #pragma unroll
    for (int t = 0; t < 4; t++) Wl[tid + t*256] = Wte[tid + t*256];
    if (tid < H) Bl[tid] = bte[tid];
    __syncthreads();
    int idx = blockIdx.x*256 + tid;
    if (idx >= T*32) return;
    int t = idx >> 5, q = (idx & 31) << 2;
    float4 acc = *(float4*)(&Bl[q]);
    #pragma unroll
    for (int k = 0; k < 8; k++){
        float s = tf[(size_t)t*8 + k];
        float4 w = *(float4*)(&Wl[k*H + q]);
        acc.x += s*w.x; acc.y += s*w.y; acc.z += s*w.z; acc.w += s*w.w;
    }
    ushort4 o;
    o.x = f2bf(acc.x); o.y = f2bf(acc.y); o.z = f2bf(acc.z); o.w = f2bf(acc.w);
    *(ushort4*)(out + (size_t)t*H + q) = o;
}

// prefix embedding + zero small accumulators + all softmax slots
__global__ void k_init_small(const float* __restrict__ pe, int plen,
                             const float* __restrict__ Wpr, const float* __restrict__ bpr,
                             float* __restrict__ prefix, float* __restrict__ meanP,
                             float* __restrict__ meanT, float* __restrict__ slots)
{
    int c = threadIdx.x;  // 128 threads
    float a = bpr[c];
    for (int k = 0; k < plen; k++) a += pe[k]*Wpr[k*H + c];
    prefix[c] = a;
    meanP[c] = 0.f;
    meanT[c] = 0.f;
    if (c < 16) slots[c] = 0.f;   // fkey-space 0 == -inf
}

// ---------------- weight transpose + bf16 convert ----------------
// per layer l: WT layout [p2tT 128x128][t2pT 128x128][tuT 128x256][puT 128x256]
__global__ __launch_bounds__(256) void k_wconv(
    const float* __restrict__ p2t_W, const float* __restrict__ t2p_W,
    const float* __restrict__ tu_W,  const float* __restrict__ pu_W,
    ushort_t* __restrict__ WT, int total)
{
    int e = blockIdx.x*256 + threadIdx.x;
    if (e >= total) return;
    int l = e / 98304, o = e - l*98304;
    const float* src; int K, oo;
    if (o < 16384)      { src = p2t_W + (size_t)l*16384; K = 128; oo = o; }
    else if (o < 32768) { src = t2p_W + (size_t)l*16384; K = 128; oo = o - 16384; }
    else if (o < 65536) { src = tu_W  + (size_t)l*32768; K = 256; oo = o - 32768; }
    else                { src = pu_W  + (size_t)l*32768; K = 256; oo = o - 65536; }
    int n = oo / K, k = oo - n*K;
    WT[e] = f2bf(src[(size_t)k*H + n]);
}

// ---------------- CSR build ----------------
__global__ __launch_bounds__(256) void k_zero_ints(int* __restrict__ p, int n)
{
    int i = blockIdx.x*256 + threadIdx.x;
    int stride = gridDim.x*256;
    for (; i < n; i += stride) p[i] = 0;
}

__global__ __launch_bounds__(256) void k_hist(
    const int* __restrict__ src, const int* __restrict__ dst, int E,
    int* __restrict__ deg, int* __restrict__ cnt)
{
    int i = blockIdx.x*256 + threadIdx.x;
    int stride = gridDim.x*256;
    for (; i < E; i += stride){
        atomicAdd(&deg[src[i]], 1);
        atomicAdd(&cnt[dst[i]], 1);
    }
}

// ---- multi-block exclusive scan (chunk = 1024 per block) ----
// pass 1: per-block sums
__global__ __launch_bounds__(256) void k_scan_part(
    const int* __restrict__ cnt, int N, int* __restrict__ bsum)
{
    __shared__ int wsum[4];
    int tid = threadIdx.x, lane = tid & 63, wid = tid >> 6;
    int base = blockIdx.x*1024 + tid*4;
    int4 v = make_int4(0,0,0,0);
    if (base + 3 < N) v = *(const int4*)(cnt + base);
    else {
        if (base+0 < N) v.x = cnt[base+0];
        if (base+1 < N) v.y = cnt[base+1];
        if (base+2 < N) v.z = cnt[base+2];
    }
    int s = v.x + v.y + v.z + v.w;
    #pragma unroll
    for (int o = 1; o < 64; o <<= 1) s += __shfl_xor(s, o);
    if (lane == 0) wsum[wid] = s;
    __syncthreads();
    if (tid == 0) bsum[blockIdx.x] = wsum[0] + wsum[1] + wsum[2] + wsum[3];
}

// pass 2: single block exclusive-scans bsum[0..nb) in place (nb <= 256)
__global__ __launch_bounds__(256) void k_scan_bsum(int* __restrict__ bsum, int nb)
{
    __shared__ int wsum[4];
    int tid = threadIdx.x, lane = tid & 63, wid = tid >> 6;
    int x = (tid < nb) ? bsum[tid] : 0;
    int inc = x;
    #pragma unroll
    for (int o = 1; o < 64; o <<= 1){
        int u = __shfl_up(inc, o);
        if (lane >= o) inc += u;
    }
    if (lane == 63) wsum[wid] = inc;
    __syncthreads();
    int woff = 0;
    if (wid > 0) woff += wsum[0];
    if (wid > 1) woff += wsum[1];
    if (wid > 2) woff += wsum[2];
    if (tid < nb) bsum[tid] = woff + inc - x;
}

// pass 3: re-scan chunk with block offset -> rp; zero cnt (cursor reuse); rp[N]=E
__global__ __launch_bounds__(256) void k_scan_final(
    int* __restrict__ cnt, int N, const int* __restrict__ bsum,
    int* __restrict__ rp, int E)
{
    __shared__ int wsum[4];
    int tid = threadIdx.x, lane = tid & 63, wid = tid >> 6;
    int base = blockIdx.x*1024 + tid*4;
    int4 v = make_int4(0,0,0,0);
    if (base + 3 < N) v = *(const int4*)(cnt + base);
    else {
        if (base+0 < N) v.x = cnt[base+0];
        if (base+1 < N) v.y = cnt[base+1];
        if (base+2 < N) v.z = cnt[base+2];
    }
    int t0 = v.x, t1 = t0 + v.y, t2 = t1 + v.z, t3 = t2 + v.w;
    int inc = t3;
    #pragma unroll
    for (int o = 1; o < 64; o <<= 1){
        int u = __shfl_up(inc, o);
        if (lane >= o) inc += u;
    }
    if (lane == 63) wsum[wid] = inc;
    __syncthreads();
    int woff = 0;
    if (wid > 0) woff += wsum[0];
    if (wid > 1) woff += wsum[1];
    if (wid > 2) woff += wsum[2];
    int off = bsum[blockIdx.x] + woff + inc - t3;   // exclusive prefix for this thread
    if (base+0 < N){ rp[base+0] = off;      cnt[base+0] = 0; }
    if (base+1 < N){ rp[base+1] = off + t0; cnt[base+1] = 0; }
    if (base+2 < N){ rp[base+2] = off + t1; cnt[base+2] = 0; }
    if (base+3 < N){ rp[base+3] = off + t2; cnt[base+3] = 0; }
    if (blockIdx.x == 0 && tid == 0) rp[N] = E;
}

__global__ __launch_bounds__(256) void k_fill(
    const int* __restrict__ src, const int* __restrict__ dst, int E,
    const int* __restrict__ rp, int* __restrict__ cur, int* __restrict__ csr)
{
    int i = blockIdx.x*256 + threadIdx.x;
    int stride = gridDim.x*256;
    for (; i < E; i += stride){
        int d = dst[i];
        int pos = rp[d] + atomicAdd(&cur[d], 1);
        csr[pos] = src[i];
    }
}

// ---------------- bf16 MFMA GEMM (+ fused epilogue) ----------------
// out[M,128](bf16) = maybe_relu( maybe(resid) + [A1|A2] @ W + bias )
// W passed as WT[n][k] (bf16). Fused score: y[r] = dot(out[r,:], aw)+ab; max->Mkey
// 128x128 tile, BK=32, 256 threads = 4 waves in 2x2 quadrants, 4x4 mfma tiles/wave.
__global__ __launch_bounds__(256) void k_gemm_bf(
    const ushort_t* __restrict__ A1, const ushort_t* __restrict__ A2,
    const ushort_t* __restrict__ WT, const float* __restrict__ bias,
    const ushort_t* __restrict__ resid, ushort_t* __restrict__ out,
    int M, int K, int relu,
    const float* __restrict__ aw, const float* __restrict__ abp,
    float* __restrict__ y, unsigned* __restrict__ Mkey)
{
    __shared__ ushort_t As[128*40];   // [row][k] stride 40
    __shared__ ushort_t Bs[128*40];   // [n][k]
    __shared__ float bl[H];
    __shared__ float awl[H];
    __shared__ float ybuf[H];
    int tid = threadIdx.x;
    int lane = tid & 63, wid = tid >> 6;
    int wm = wid & 1, wn = wid >> 1;
    int quad = lane >> 4, l15 = lane & 15;
    int row0 = blockIdx.x * 128;

    if (tid < H){
        bl[tid] = bias[tid];
        if (aw){ awl[tid] = aw[tid]; ybuf[tid] = 0.f; }
    }

    floatx4 acc[4][4];
    #pragma unroll
    for (int i = 0; i < 4; i++)
        #pragma unroll
        for (int j = 0; j < 4; j++) acc[i][j] = (floatx4)0.f;

    int r = tid >> 2, c = (tid & 3) * 8;          // staging: 4 threads/row, 16B each
    for (int k0 = 0; k0 < K; k0 += 32){
        const ushort_t* Asrc; int kl;
        if (k0 < H){ Asrc = A1; kl = k0; } else { Asrc = A2; kl = k0 - H; }
        #pragma unroll
        for (int t = 0; t < 2; t++){
            int rr = r + t*64;
            int rg = row0 + rr;
            int4 v = make_int4(0,0,0,0);
            if (rg < M) v = *(const int4*)(Asrc + (size_t)rg*H + kl + c);
            *(int4*)(&As[rr*40 + c]) = v;
            *(int4*)(&Bs[rr*40 + c]) = *(const int4*)(WT + (size_t)rr*K + k0 + c);
        }
        __syncthreads();
        short8 a_frag[4], b_frag[4];
        #pragma unroll
        for (int i = 0; i < 4; i++)
            a_frag[i] = *(const short8*)(&As[(wm*64 + i*16 + l15)*40 + quad*8]);
        #pragma unroll
        for (int j = 0; j < 4; j++)
            b_frag[j] = *(const short8*)(&Bs[(wn*64 + j*16 + l15)*40 + quad*8]);
        #pragma unroll
        for (int i = 0; i < 4; i++)
            #pragma unroll
            for (int j = 0; j < 4; j++)
                acc[i][j] = __builtin_amdgcn_mfma_f32_16x16x32_bf16(
                                a_frag[i], b_frag[j], acc[i][j], 0, 0, 0);
        __syncthreads();
    }

    // epilogue: D[row][col], row = wm*64+i*16+quad*4+rr, col = wn*64+j*16+l15
    float pacc[4][4];
    #pragma unroll
    for (int i = 0; i < 4; i++)
        #pragma unroll
        for (int rr = 0; rr < 4; rr++) pacc[i][rr] = 0.f;

    #pragma unroll
    for (int i = 0; i < 4; i++){
        int mbase = wm*64 + i*16 + quad*4;
        #pragma unroll
        for (int j = 0; j < 4; j++){
            int col = wn*64 + j*16 + l15;
            float bcol = bl[col];
            #pragma unroll
            for (int rr = 0; rr < 4; rr++){
                int grow = row0 + mbase + rr;
                if (grow >= M) continue;
                float v = acc[i][j][rr] + bcol;
                if (resid) v += bf2f(resid[(size_t)grow*H + col]);
                if (relu)  v = fmaxf(v, 0.f);
                out[(size_t)grow*H + col] = f2bf(v);
                if (aw) pacc[i][rr] += v * awl[col];
            }
        }
    }
    if (aw){
        #pragma unroll
        for (int i = 0; i < 4; i++)
            #pragma unroll
            for (int rr = 0; rr < 4; rr++){
                float p = pacc[i][rr];
                #pragma unroll
                for (int o = 1; o < 16; o <<= 1) p += __shfl_xor(p, o);
                if (l15 == 0) atomicAdd(&ybuf[wm*64 + i*16 + quad*4 + rr], p);
            }
        __syncthreads();
        if (tid < H){
            int grow = row0 + tid;
            float s = -3.402823466e38f;
            if (grow < M){
                s = ybuf[tid] + abp[0];
                y[grow] = s;
            }
            float m = s;
            #pragma unroll
            for (int o = 1; o < 64; o <<= 1) m = fmaxf(m, __shfl_xor(m, o));
            if (lane == 0) atomicMax(Mkey, fkey(m));
        }
    }
}

// ---------------- softmax denominator: sum over nodes of deg * exp(y - M) -----
__global__ __launch_bounds__(256) void k_denom(
    const int* __restrict__ deg, int N, const float* __restrict__ y,
    const unsigned* __restrict__ Mkey, float* __restrict__ Sp)
{
    __shared__ float red[256];
    int tid = threadIdx.x;
    int gid = blockIdx.x*256 + tid, stride = gridDim.x*256;
    float Mv = funkey(Mkey[0]);
    float ls = 0.f;
    for (int n = gid; n < N; n += stride){
        int d = deg[n];
        if (d) ls += (float)d * expf(y[n] - Mv);
    }
    red[tid] = ls;
    __syncthreads();
    for (int s = 128; s > 0; s >>= 1){
        if (tid < s) red[tid] += red[tid + s];
        __syncthreads();
    }
    if (tid == 0) atomicAdd(Sp, red[0]);
}

// ---------------- CSR gather (bf16 X -> bf16 Mb) ----------------
__global__ __launch_bounds__(256) void k_gather(
    const int* __restrict__ rp, const int* __restrict__ csr, int Nrow,
    const float* __restrict__ y, const ushort_t* __restrict__ X,
    ushort_t* __restrict__ Mb, const unsigned* __restrict__ Mkey,
    const float* __restrict__ Sp)
{
    int lane = threadIdx.x & 63, w = threadIdx.x >> 6;
    int r = blockIdx.x*4 + w;                 // one wave per dst row
    if (r >= Nrow) return;
    float Mv = funkey(Mkey[0]);
    float invS = 1.f / Sp[0];
    int j0 = rp[r], j1 = rp[r+1];
    const unsigned* X2 = (const unsigned*)X;  // 2 bf16 per lane, row = 64 uints
    float ax = 0.f, ay = 0.f;
    for (int j = j0; j < j1; j++){
        int s = csr[j];                        // uniform across wave
        float wg = expf(y[s] - Mv) * invS;
        unsigned u = X2[(size_t)s*64 + lane];
        ax += wg * __uint_as_float(u << 16);
        ay += wg * __uint_as_float(u & 0xffff0000u);
    }
    unsigned o = ((unsigned)f2bf(ay) << 16) | (unsigned)f2bf(ax);
    ((unsigned*)Mb)[(size_t)r*64 + lane] = o;
}

// ---------------- column mean accumulator (bf16 input) ----------------
__global__ __launch_bounds__(256) void k_colmean(
    const ushort_t* __restrict__ h, int N, float* __restrict__ accum)
{
    __shared__ float cs[256];
    int tid = threadIdx.x;
    int c = tid & 127, rr = tid >> 7;
    float a = 0.f;
    for (int r = blockIdx.x*2 + rr; r < N; r += gridDim.x*2)
        a += bf2f(h[(size_t)r*H + c]);
    cs[tid] = a;
    __syncthreads();
    if (tid < 128) atomicAdd(&accum[c], cs[tid] + cs[tid + 128]);
}

// ---------------- tiny MLP head ----------------
__global__ __launch_bounds__(256) void k_head(
    const float* __restrict__ meanP, const float* __restrict__ meanT,
    float invP, float invT,
    const float* __restrict__ Wpp, const float* __restrict__ bpp,
    const float* __restrict__ Wtp, const float* __restrict__ btp,
    const float* __restrict__ prefix,
    const float* __restrict__ W1, const float* __restrict__ b1,
    const float* __restrict__ W2, const float* __restrict__ b2,
    float* __restrict__ h2g)
{
    __shared__ float comb[384];
    __shared__ float h1s[256];
    int tid = threadIdx.x;
    if (tid < 128){
        float a = bpp[tid];
        for (int k = 0; k < 128; k++) a += meanP[k]*invP*Wpp[k*H + tid];
        comb[tid] = a;
        comb[256 + tid] = prefix[tid];
    } else {
        int c = tid - 128;
        float a = btp[c];
        for (int k = 0; k < 128; k++) a += meanT[k]*invT*Wtp[k*H + c];
        comb[128 + c] = a;
    }
    __syncthreads();
    {
        float a = b1[tid];
        for (int k = 0; k < 384; k++) a += comb[k]*W1[k*256 + tid];
        h1s[tid] = fmaxf(a, 0.f);
    }
    __syncthreads();
    if (tid < 128){
        float a = b2[tid];
        for (int k = 0; k < 256; k++) a += h1s[k]*W2[k*H + tid];
        h2g[tid] = fmaxf(a, 0.f);
    }
}

// ---------------- logits + sigmoid ----------------
__global__ __launch_bounds__(256) void k_logits(
    const float* __restrict__ h2g, const float* __restrict__ W3,
    const float* __restrict__ b3, float* __restrict__ out, int T)
{
    __shared__ float h2l[128];
    int tid = threadIdx.x;
    if (tid < 128) h2l[tid] = h2g[tid];
    __syncthreads();
    int t = blockIdx.x*256 + tid;
    if (t >= T) return;
    float a = b3[t];
    #pragma unroll 8
    for (int k = 0; k < 128; k++) a += h2l[k]*W3[(size_t)k*T + t];
    out[t] = 1.f/(1.f + expf(-a));
}

// ---------------- launch ----------------
extern "C" void kernel_launch(void* const* d_in, const int* in_sizes, int n_in,
                              void* d_out, int out_size, void* d_ws, size_t ws_size,
                              hipStream_t stream)
{
    (void)n_in; (void)out_size; (void)ws_size;
    const float* pf    = (const float*)d_in[0];
    const float* tf    = (const float*)d_in[1];
    const float* pe    = (const float*)d_in[2];
    const int*   pre   = (const int*)d_in[3];
    const int*   post  = (const int*)d_in[4];
    const float* W_pe  = (const float*)d_in[5];
    const float* b_pe  = (const float*)d_in[6];
    const float* W_te  = (const float*)d_in[7];
    const float* b_te  = (const float*)d_in[8];
    const float* W_pr  = (const float*)d_in[9];
    const float* b_pr  = (const float*)d_in[10];
    const float* p2t_W = (const float*)d_in[11];
    const float* p2t_b = (const float*)d_in[12];
    const float* t2p_W = (const float*)d_in[13];
    const float* t2p_b = (const float*)d_in[14];
    const float* pu_W  = (const float*)d_in[15];
    const float* pu_b  = (const float*)d_in[16];
    const float* tu_W  = (const float*)d_in[17];
    const float* tu_b  = (const float*)d_in[18];
    const float* pa_W  = (const float*)d_in[19];
    const float* pa_b  = (const float*)d_in[20];
    const float* ta_W  = (const float*)d_in[21];
    const float* ta_b  = (const float*)d_in[22];
    const float* W_pp  = (const float*)d_in[23];
    const float* b_pp  = (const float*)d_in[24];
    const float* W_tp  = (const float*)d_in[25];
    const float* b_tp  = (const float*)d_in[26];
    const float* W1    = (const float*)d_in[27];
    const float* b1    = (const float*)d_in[28];
    const float* W2    = (const float*)d_in[29];
    const float* b2    = (const float*)d_in[30];
    const float* W3    = (const float*)d_in[31];
    const float* b3    = (const float*)d_in[32];

    int P = in_sizes[0];
    int T = in_sizes[1] / 8;
    int E = in_sizes[3] / 2;
    int plen = in_sizes[2];
    int L = in_sizes[11] / (H*H);

    float* ws = (float*)d_ws;
    size_t fP = (size_t)P*H, fT = (size_t)T*H;
    size_t fN = (fP > fT) ? fP : fT;
    int   Nmax = (P > T) ? P : T;

    float* yb = ws;                       // [Nmax] fp32 scores
    float* sc = yb + Nmax;                // 16 softmax slots + small vectors
    float* meanP   = sc + 16;
    float* meanT   = sc + 144;
    float* prefix  = sc + 272;
    float* h2g     = sc + 400;            // end at sc+544 (16B aligned)

    ushort_t* bh = (ushort_t*)(sc + 544);
    ushort_t* place_h = bh;               // [P,128] bf16
    ushort_t* trans_h = place_h + fP;     // [T,128]
    ushort_t* Xb      = trans_h + fT;     // [Nmax,128]
    ushort_t* Mb      = Xb + fN;          // [Nmax,128]
    ushort_t* WTb     = Mb + fN;          // L*98304 bf16 transposed weights

    int* iw = (int*)(WTb + (size_t)L*98304);
    int* cntPre  = iw;                 // [T]
    int* degPre  = cntPre + T;         // [P]
    int* cntPost = degPre + P;         // [P]
    int* degPost = cntPost + P;        // [T]
    int* rpPre   = degPost + T;        // [T+1]
    int* rpPost  = rpPre + (T + 1);    // [P+1]
    int* csrPre  = rpPost + (P + 2);   // [E]
    int* csrPost = csrPre + E;         // [E]
    int* bsum    = csrPost + E;        // [256] scan block sums

    const int* pre_src  = pre;          const int* pre_dst  = pre + E;
    const int* post_src = post;         const int* post_dst = post + E;

    int g128P = (P + 127)/128, g128T = (T + 127)/128;
    int wtot = L*98304;
    int nbT = (T + 1023)/1024, nbP = (P + 1023)/1024;

    k_init_small<<<1, 128, 0, stream>>>(pe, plen, W_pr, b_pr, prefix, meanP, meanT, sc);
    k_wconv<<<(wtot + 255)/256, 256, 0, stream>>>(p2t_W, t2p_W, tu_W, pu_W, WTb, wtot);
    k_zero_ints<<<512, 256, 0, stream>>>(iw, 2*(P + T));
    k_hist<<<1024, 256, 0, stream>>>(pre_src, pre_dst, E, degPre, cntPre);
    k_hist<<<1024, 256, 0, stream>>>(post_src, post_dst, E, degPost, cntPost);
    // multi-block exclusive scans (replaces the 87 µs single-block scan)
    k_scan_part<<<nbT, 256, 0, stream>>>(cntPre, T, bsum);
    k_scan_bsum<<<1, 256, 0, stream>>>(bsum, nbT);
    k_scan_final<<<nbT, 256, 0, stream>>>(cntPre, T, bsum, rpPre, E);
    k_fill<<<1024, 256, 0, stream>>>(pre_src, pre_dst, E, rpPre, cntPre, csrPre);
    k_scan_part<<<nbP, 256, 0, stream>>>(cntPost, P, bsum);
    k_scan_bsum<<<1, 256, 0, stream>>>(bsum, nbP);
    k_scan_final<<<nbP, 256, 0, stream>>>(cntPost, P, bsum, rpPost, E);
    k_fill<<<1024, 256, 0, stream>>>(post_src, post_dst, E, rpPost, cntPost, csrPost);

    k_embed_place<<<(P*32 + 255)/256, 256, 0, stream>>>(pf, W_pe, b_pe, place_h, P);
    k_embed_trans<<<(T*32 + 255)/256, 256, 0, stream>>>(tf, W_te, b_te, trans_h, T);

    for (int l = 0; l < L; l++){
        const ushort_t* WTl  = WTb + (size_t)l*98304;
        const ushort_t* p2tT = WTl;
        const ushort_t* t2pT = WTl + 16384;
        const ushort_t* tuT  = WTl + 32768;
        const ushort_t* puT  = WTl + 65536;
        const float* p2tb = p2t_b + (size_t)l*H;
        const float* t2pb = t2p_b + (size_t)l*H;
        const float* pub  = pu_b  + (size_t)l*H;
        const float* tub  = tu_b  + (size_t)l*H;
        const float* paW  = pa_W + (size_t)l*H;   const float* pab = pa_b + l;
        const float* taW  = ta_W + (size_t)l*H;   const float* tab = ta_b + l;
        unsigned* MkA = (unsigned*)(sc + l*4 + 0);   float* SpA = sc + l*4 + 1;
        unsigned* MkB = (unsigned*)(sc + l*4 + 2);   float* SpB = sc + l*4 + 3;

        // phase A: place -> transition (scores over place nodes fused)
        k_gemm_bf<<<g128P, 256, 0, stream>>>(place_h, nullptr, p2tT, p2tb, nullptr, Xb,
                                             P, H, 0, taW, tab, yb, MkA);
        k_denom<<<128, 256, 0, stream>>>(degPre, P, yb, MkA, SpA);
        k_gather<<<(T + 3)/4, 256, 0, stream>>>(rpPre, csrPre, T, yb, Xb, Mb, MkA, SpA);

        // phase B: transform from OLD trans_h (+ its scores)
        k_gemm_bf<<<g128T, 256, 0, stream>>>(trans_h, nullptr, t2pT, t2pb, nullptr, Xb,
                                             T, H, 0, paW, pab, yb, MkB);
        k_denom<<<128, 256, 0, stream>>>(degPost, T, yb, MkB, SpB);

        // transition update (consumes Mb = trans_msg), in-place
        k_gemm_bf<<<g128T, 256, 0, stream>>>(trans_h, Mb, tuT, tub, trans_h, trans_h,
                                             T, 2*H, 1, nullptr, nullptr, nullptr, nullptr);

        // place messages, then place update in-place
        k_gather<<<(P + 3)/4, 256, 0, stream>>>(rpPost, csrPost, P, yb, Xb, Mb, MkB, SpB);
        k_gemm_bf<<<g128P, 256, 0, stream>>>(place_h, Mb, puT, pub, place_h, place_h,
                                             P, 2*H, 1, nullptr, nullptr, nullptr, nullptr);
    }

    k_colmean<<<256, 256, 0, stream>>>(place_h, P, meanP);
    k_colmean<<<256, 256, 0, stream>>>(trans_h, T, meanT);
    k_head<<<1, 256, 0, stream>>>(meanP, meanT, 1.f/(float)P, 1.f/(float)T,
                                  W_pp, b_pp, W_tp, b_tp, prefix, W1, b1, W2, b2, h2g);
    k_logits<<<(T + 255)/256, 256, 0, stream>>>(h2g, W3, b3, (float*)d_out, T);
}

// Round 6
// 1119.707 us; speedup vs baseline: 2.1917x; 1.2184x over previous
//
#include <hip/hip_runtime.h>
#include <cstddef>

#define H 128

typedef unsigned short ushort_t;
typedef __attribute__((ext_vector_type(8))) short short8;
typedef __attribute__((ext_vector_type(4))) float floatx4;

// ---------------- helpers ----------------
__device__ __forceinline__ unsigned fkey(float f){
    unsigned u = __float_as_uint(f);
    return (u & 0x80000000u) ? ~u : (u | 0x80000000u);
}
__device__ __forceinline__ float funkey(unsigned k){
    unsigned u = (k & 0x80000000u) ? (k ^ 0x80000000u) : ~k;
    return __uint_as_float(u);
}
__device__ __forceinline__ ushort_t f2bf(float f){
    unsigned u = __float_as_uint(f);
    u += 0x7fffu + ((u >> 16) & 1u);      // round-to-nearest-even
    return (ushort_t)(u >> 16);
}
__device__ __forceinline__ float bf2f(ushort_t h){
    return __uint_as_float(((unsigned)h) << 16);
}

// ---------------- embeddings (write bf16 states) ----------------
__global__ __launch_bounds__(256) void k_embed_place(
    const float* __restrict__ pf, const float* __restrict__ Wpe,
    const float* __restrict__ bpe, ushort_t* __restrict__ out, int P)
{
    int idx = blockIdx.x*256 + threadIdx.x;     // 4-elem group index over P*32
    if (idx >= P*32) return;
    int p = idx >> 5, q = (idx & 31) << 2;
    float v = pf[p];
    float4 w = *(const float4*)(Wpe + q);
    float4 b = *(const float4*)(bpe + q);
    ushort4 o;
    o.x = f2bf(v*w.x + b.x); o.y = f2bf(v*w.y + b.y);
    o.z = f2bf(v*w.z + b.z); o.w = f2bf(v*w.w + b.w);
    *(ushort4*)(out + (size_t)p*H + q) = o;
}

__global__ __launch_bounds__(256) void k_embed_trans(
    const float* __restrict__ tf, const float* __restrict__ Wte,
    const float* __restrict__ bte, ushort_t* __restrict__ out, int T)
{
    __shared__ float Wl[8*H];
    __shared__ float Bl[H];
    int tid = threadIdx.x;
    #pragma unroll
    for (int t = 0; t < 4; t++) Wl[tid + t*256] = Wte[tid + t*256];
    if (tid < H) Bl[tid] = bte[tid];
    __syncthreads();
    int idx = blockIdx.x*256 + tid;
    if (idx >= T*32) return;
    int t = idx >> 5, q = (idx & 31) << 2;
    float4 acc = *(float4*)(&Bl[q]);
    #pragma unroll
    for (int k = 0; k < 8; k++){
        float s = tf[(size_t)t*8 + k];
        float4 w = *(float4*)(&Wl[k*H + q]);
        acc.x += s*w.x; acc.y += s*w.y; acc.z += s*w.z; acc.w += s*w.w;
    }
    ushort4 o;
    o.x = f2bf(acc.x); o.y = f2bf(acc.y); o.z = f2bf(acc.z); o.w = f2bf(acc.w);
    *(ushort4*)(out + (size_t)t*H + q) = o;
}

// prefix embedding + zero small accumulators + all softmax slots
__global__ void k_init_small(const float* __restrict__ pe, int plen,
                             const float* __restrict__ Wpr, const float* __restrict__ bpr,
                             float* __restrict__ prefix, float* __restrict__ meanP,
                             float* __restrict__ meanT, float* __restrict__ slots)
{
    int c = threadIdx.x;  // 128 threads
    float a = bpr[c];
    for (int k = 0; k < plen; k++) a += pe[k]*Wpr[k*H + c];
    prefix[c] = a;
    meanP[c] = 0.f;
    meanT[c] = 0.f;
    if (c < 16) slots[c] = 0.f;   // fkey-space 0 == -inf
}

// ---------------- weight transpose + bf16 convert ----------------
// per layer l: WT layout [p2tT 128x128][t2pT 128x128][tuT 128x256][puT 128x256]
__global__ __launch_bounds__(256) void k_wconv(
    const float* __restrict__ p2t_W, const float* __restrict__ t2p_W,
    const float* __restrict__ tu_W,  const float* __restrict__ pu_W,
    ushort_t* __restrict__ WT, int total)
{
    int e = blockIdx.x*256 + threadIdx.x;
    if (e >= total) return;
    int l = e / 98304, o = e - l*98304;
    const float* src; int K, oo;
    if (o < 16384)      { src = p2t_W + (size_t)l*16384; K = 128; oo = o; }
    else if (o < 32768) { src = t2p_W + (size_t)l*16384; K = 128; oo = o - 16384; }
    else if (o < 65536) { src = tu_W  + (size_t)l*32768; K = 256; oo = o - 32768; }
    else                { src = pu_W  + (size_t)l*32768; K = 256; oo = o - 65536; }
    int n = oo / K, k = oo - n*K;
    WT[e] = f2bf(src[(size_t)k*H + n]);
}

// ---------------- CSR build ----------------
__global__ __launch_bounds__(256) void k_zero_ints(int* __restrict__ p, int n)
{
    int i = blockIdx.x*256 + threadIdx.x;
    int stride = gridDim.x*256;
    for (; i < n; i += stride) p[i] = 0;
}

// both edge lists in one kernel
__global__ __launch_bounds__(256) void k_hist2(
    const int* __restrict__ preS, const int* __restrict__ preD,
    const int* __restrict__ postS, const int* __restrict__ postD, int E,
    int* __restrict__ degPre, int* __restrict__ cntPre,
    int* __restrict__ degPost, int* __restrict__ cntPost)
{
    int i = blockIdx.x*256 + threadIdx.x;
    int stride = gridDim.x*256;
    for (; i < E; i += stride){
        atomicAdd(&degPre[preS[i]], 1);
        atomicAdd(&cntPre[preD[i]], 1);
        atomicAdd(&degPost[postS[i]], 1);
        atomicAdd(&cntPost[postD[i]], 1);
    }
}

// ---- multi-block exclusive scan (chunk = 1024 per block) ----
__global__ __launch_bounds__(256) void k_scan_part(
    const int* __restrict__ cnt, int N, int* __restrict__ bsum)
{
    __shared__ int wsum[4];
    int tid = threadIdx.x, lane = tid & 63, wid = tid >> 6;
    int base = blockIdx.x*1024 + tid*4;
    int4 v = make_int4(0,0,0,0);
    if (base + 3 < N) v = *(const int4*)(cnt + base);
    else {
        if (base+0 < N) v.x = cnt[base+0];
        if (base+1 < N) v.y = cnt[base+1];
        if (base+2 < N) v.z = cnt[base+2];
    }
    int s = v.x + v.y + v.z + v.w;
    #pragma unroll
    for (int o = 1; o < 64; o <<= 1) s += __shfl_xor(s, o);
    if (lane == 0) wsum[wid] = s;
    __syncthreads();
    if (tid == 0) bsum[blockIdx.x] = wsum[0] + wsum[1] + wsum[2] + wsum[3];
}

__global__ __launch_bounds__(256) void k_scan_bsum(int* __restrict__ bsum, int nb)
{
    __shared__ int wsum[4];
    int tid = threadIdx.x, lane = tid & 63, wid = tid >> 6;
    int x = (tid < nb) ? bsum[tid] : 0;
    int inc = x;
    #pragma unroll
    for (int o = 1; o < 64; o <<= 1){
        int u = __shfl_up(inc, o);
        if (lane >= o) inc += u;
    }
    if (lane == 63) wsum[wid] = inc;
    __syncthreads();
    int woff = 0;
    if (wid > 0) woff += wsum[0];
    if (wid > 1) woff += wsum[1];
    if (wid > 2) woff += wsum[2];
    if (tid < nb) bsum[tid] = woff + inc - x;
}

__global__ __launch_bounds__(256) void k_scan_final(
    int* __restrict__ cnt, int N, const int* __restrict__ bsum,
    int* __restrict__ rp, int E)
{
    __shared__ int wsum[4];
    int tid = threadIdx.x, lane = tid & 63, wid = tid >> 6;
    int base = blockIdx.x*1024 + tid*4;
    int4 v = make_int4(0,0,0,0);
    if (base + 3 < N) v = *(const int4*)(cnt + base);
    else {
        if (base+0 < N) v.x = cnt[base+0];
        if (base+1 < N) v.y = cnt[base+1];
        if (base+2 < N) v.z = cnt[base+2];
    }
    int t0 = v.x, t1 = t0 + v.y, t2 = t1 + v.z, t3 = t2 + v.w;
    int inc = t3;
    #pragma unroll
    for (int o = 1; o < 64; o <<= 1){
        int u = __shfl_up(inc, o);
        if (lane >= o) inc += u;
    }
    if (lane == 63) wsum[wid] = inc;
    __syncthreads();
    int woff = 0;
    if (wid > 0) woff += wsum[0];
    if (wid > 1) woff += wsum[1];
    if (wid > 2) woff += wsum[2];
    int off = bsum[blockIdx.x] + woff + inc - t3;
    if (base+0 < N){ rp[base+0] = off;      cnt[base+0] = 0; }
    if (base+1 < N){ rp[base+1] = off + t0; cnt[base+1] = 0; }
    if (base+2 < N){ rp[base+2] = off + t1; cnt[base+2] = 0; }
    if (base+3 < N){ rp[base+3] = off + t2; cnt[base+3] = 0; }
    if (blockIdx.x == 0 && tid == 0) rp[N] = E;
}

// both CSR fills in one kernel
__global__ __launch_bounds__(256) void k_fill2(
    const int* __restrict__ preS, const int* __restrict__ preD,
    const int* __restrict__ postS, const int* __restrict__ postD, int E,
    const int* __restrict__ rpPre, int* __restrict__ curPre, int* __restrict__ csrPre,
    const int* __restrict__ rpPost, int* __restrict__ curPost, int* __restrict__ csrPost)
{
    int i = blockIdx.x*256 + threadIdx.x;
    int stride = gridDim.x*256;
    for (; i < E; i += stride){
        int d = preD[i];
        csrPre[rpPre[d] + atomicAdd(&curPre[d], 1)] = preS[i];
        int d2 = postD[i];
        csrPost[rpPost[d2] + atomicAdd(&curPost[d2], 1)] = postS[i];
    }
}

// ---------------- bf16 MFMA GEMM (+ fused epilogue) ----------------
// out[M,128](bf16) = maybe_relu( maybe(resid) + [A1|A2] @ W + bias )
// W passed as WT[n][k] (bf16). Optional fused score (aw): y[r], max->Mkey.
// Optional fused column-sum (colsum): colsum[c] += sum_rows out[r][c] (pooling).
__global__ __launch_bounds__(256) void k_gemm_bf(
    const ushort_t* __restrict__ A1, const ushort_t* __restrict__ A2,
    const ushort_t* __restrict__ WT, const float* __restrict__ bias,
    const ushort_t* __restrict__ resid, ushort_t* __restrict__ out,
    int M, int K, int relu,
    const float* __restrict__ aw, const float* __restrict__ abp,
    float* __restrict__ y, unsigned* __restrict__ Mkey,
    float* __restrict__ colsum)
{
    __shared__ ushort_t As[128*40];   // [row][k] stride 40
    __shared__ ushort_t Bs[128*40];   // [n][k]
    __shared__ float bl[H];
    __shared__ float awl[H];
    __shared__ float ybuf[H];
    __shared__ float csum[H];
    int tid = threadIdx.x;
    int lane = tid & 63, wid = tid >> 6;
    int wm = wid & 1, wn = wid >> 1;
    int quad = lane >> 4, l15 = lane & 15;
    int row0 = blockIdx.x * 128;

    if (tid < H){
        bl[tid] = bias[tid];
        if (aw){ awl[tid] = aw[tid]; ybuf[tid] = 0.f; }
        if (colsum) csum[tid] = 0.f;
    }

    floatx4 acc[4][4];
    #pragma unroll
    for (int i = 0; i < 4; i++)
        #pragma unroll
        for (int j = 0; j < 4; j++) acc[i][j] = (floatx4)0.f;

    int r = tid >> 2, c = (tid & 3) * 8;          // staging: 4 threads/row, 16B each
    for (int k0 = 0; k0 < K; k0 += 32){
        const ushort_t* Asrc; int kl;
        if (k0 < H){ Asrc = A1; kl = k0; } else { Asrc = A2; kl = k0 - H; }
        #pragma unroll
        for (int t = 0; t < 2; t++){
            int rr = r + t*64;
            int rg = row0 + rr;
            int4 v = make_int4(0,0,0,0);
            if (rg < M) v = *(const int4*)(Asrc + (size_t)rg*H + kl + c);
            *(int4*)(&As[rr*40 + c]) = v;
            *(int4*)(&Bs[rr*40 + c]) = *(const int4*)(WT + (size_t)rr*K + k0 + c);
        }
        __syncthreads();
        short8 a_frag[4], b_frag[4];
        #pragma unroll
        for (int i = 0; i < 4; i++)
            a_frag[i] = *(const short8*)(&As[(wm*64 + i*16 + l15)*40 + quad*8]);
        #pragma unroll
        for (int j = 0; j < 4; j++)
            b_frag[j] = *(const short8*)(&Bs[(wn*64 + j*16 + l15)*40 + quad*8]);
        #pragma unroll
        for (int i = 0; i < 4; i++)
            #pragma unroll
            for (int j = 0; j < 4; j++)
                acc[i][j] = __builtin_amdgcn_mfma_f32_16x16x32_bf16(
                                a_frag[i], b_frag[j], acc[i][j], 0, 0, 0);
        __syncthreads();
    }

    // epilogue: D[row][col], row = wm*64+i*16+quad*4+rr, col = wn*64+j*16+l15
    float pacc[4][4];
    #pragma unroll
    for (int i = 0; i < 4; i++)
        #pragma unroll
        for (int rr = 0; rr < 4; rr++) pacc[i][rr] = 0.f;
    float cacc[4] = {0.f, 0.f, 0.f, 0.f};

    #pragma unroll
    for (int i = 0; i < 4; i++){
        int mbase = wm*64 + i*16 + quad*4;
        #pragma unroll
        for (int j = 0; j < 4; j++){
            int col = wn*64 + j*16 + l15;
            float bcol = bl[col];
            #pragma unroll
            for (int rr = 0; rr < 4; rr++){
                int grow = row0 + mbase + rr;
                if (grow >= M) continue;
                float v = acc[i][j][rr] + bcol;
                if (resid) v += bf2f(resid[(size_t)grow*H + col]);
                if (relu)  v = fmaxf(v, 0.f);
                out[(size_t)grow*H + col] = f2bf(v);
                if (aw) pacc[i][rr] += v * awl[col];
                if (colsum) cacc[j] += v;
            }
        }
    }
    if (aw){
        #pragma unroll
        for (int i = 0; i < 4; i++)
            #pragma unroll
            for (int rr = 0; rr < 4; rr++){
                float p = pacc[i][rr];
                #pragma unroll
                for (int o = 1; o < 16; o <<= 1) p += __shfl_xor(p, o);
                if (l15 == 0) atomicAdd(&ybuf[wm*64 + i*16 + quad*4 + rr], p);
            }
        __syncthreads();
        if (tid < H){
            int grow = row0 + tid;
            float s = -3.402823466e38f;
            if (grow < M){
                s = ybuf[tid] + abp[0];
                y[grow] = s;
            }
            float m = s;
            #pragma unroll
            for (int o = 1; o < 64; o <<= 1) m = fmaxf(m, __shfl_xor(m, o));
            if (lane == 0) atomicMax(Mkey, fkey(m));
        }
    }
    if (colsum){
        #pragma unroll
        for (int j = 0; j < 4; j++)
            atomicAdd(&csum[wn*64 + j*16 + l15], cacc[j]);
        __syncthreads();
        if (tid < H) atomicAdd(&colsum[tid], csum[tid]);
    }
}

// ---------------- softmax denominator: sum over nodes of deg * exp(y - M) -----
__global__ __launch_bounds__(256) void k_denom(
    const int* __restrict__ deg, int N, const float* __restrict__ y,
    const unsigned* __restrict__ Mkey, float* __restrict__ Sp)
{
    __shared__ float red[256];
    int tid = threadIdx.x;
    int gid = blockIdx.x*256 + tid, stride = gridDim.x*256;
    float Mv = funkey(Mkey[0]);
    float ls = 0.f;
    for (int n = gid; n < N; n += stride){
        int d = deg[n];
        if (d) ls += (float)d * expf(y[n] - Mv);
    }
    red[tid] = ls;
    __syncthreads();
    for (int s = 128; s > 0; s >>= 1){
        if (tid < s) red[tid] += red[tid + s];
        __syncthreads();
    }
    if (tid == 0) atomicAdd(Sp, red[0]);
}

// accumulate 8 bf16 (one int4) into 8 fp32 with weight
__device__ __forceinline__ void acc8(float* a, int4 u, float wgt){
    a[0] += wgt*__uint_as_float(((unsigned)u.x) << 16);
    a[1] += wgt*__uint_as_float(((unsigned)u.x) & 0xffff0000u);
    a[2] += wgt*__uint_as_float(((unsigned)u.y) << 16);
    a[3] += wgt*__uint_as_float(((unsigned)u.y) & 0xffff0000u);
    a[4] += wgt*__uint_as_float(((unsigned)u.z) << 16);
    a[5] += wgt*__uint_as_float(((unsigned)u.z) & 0xffff0000u);
    a[6] += wgt*__uint_as_float(((unsigned)u.w) << 16);
    a[7] += wgt*__uint_as_float(((unsigned)u.w) & 0xffff0000u);
}

// ---------------- CSR gather: 16-lane row groups, int4 loads, 2-edge unroll ---
__global__ __launch_bounds__(256) void k_gather(
    const int* __restrict__ rp, const int* __restrict__ csr, int Nrow,
    const float* __restrict__ y, const ushort_t* __restrict__ X,
    ushort_t* __restrict__ Mb, const unsigned* __restrict__ Mkey,
    const float* __restrict__ Sp)
{
    int tid = threadIdx.x;
    int g = tid >> 4, gl = tid & 15;          // 16 groups x 16 lanes
    int r = blockIdx.x*16 + g;
    if (r >= Nrow) return;
    float Mv = funkey(Mkey[0]);
    float invS = 1.f / Sp[0];
    int j0 = rp[r], j1 = rp[r+1];
    const int4* X4 = (const int4*)X;          // row = 16 int4 (128 bf16)
    float a[8] = {0.f,0.f,0.f,0.f,0.f,0.f,0.f,0.f};
    int j = j0;
    for (; j + 1 < j1; j += 2){
        int s0 = csr[j], s1 = csr[j+1];
        float e0 = expf(y[s0] - Mv);
        float e1 = expf(y[s1] - Mv);
        int4 u0 = X4[(size_t)s0*16 + gl];
        int4 u1 = X4[(size_t)s1*16 + gl];
        acc8(a, u0, e0);
        acc8(a, u1, e1);
    }
    if (j < j1){
        int s0 = csr[j];
        float e0 = expf(y[s0] - Mv);
        int4 u0 = X4[(size_t)s0*16 + gl];
        acc8(a, u0, e0);
    }
    int4 o;
    o.x = (int)((((unsigned)f2bf(a[1]*invS)) << 16) | (unsigned)f2bf(a[0]*invS));
    o.y = (int)((((unsigned)f2bf(a[3]*invS)) << 16) | (unsigned)f2bf(a[2]*invS));
    o.z = (int)((((unsigned)f2bf(a[5]*invS)) << 16) | (unsigned)f2bf(a[4]*invS));
    o.w = (int)((((unsigned)f2bf(a[7]*invS)) << 16) | (unsigned)f2bf(a[6]*invS));
    ((int4*)Mb)[(size_t)r*16 + gl] = o;
}

// ---------------- tiny MLP head ----------------
__global__ __launch_bounds__(256) void k_head(
    const float* __restrict__ meanP, const float* __restrict__ meanT,
    float invP, float invT,
    const float* __restrict__ Wpp, const float* __restrict__ bpp,
    const float* __restrict__ Wtp, const float* __restrict__ btp,
    const float* __restrict__ prefix,
    const float* __restrict__ W1, const float* __restrict__ b1,
    const float* __restrict__ W2, const float* __restrict__ b2,
    float* __restrict__ h2g)
{
    __shared__ float comb[384];
    __shared__ float h1s[256];
    int tid = threadIdx.x;
    if (tid < 128){
        float a = bpp[tid];
        for (int k = 0; k < 128; k++) a += meanP[k]*invP*Wpp[k*H + tid];
        comb[tid] = a;
        comb[256 + tid] = prefix[tid];
    } else {
        int c = tid - 128;
        float a = btp[c];
        for (int k = 0; k < 128; k++) a += meanT[k]*invT*Wtp[k*H + c];
        comb[128 + c] = a;
    }
    __syncthreads();
    {
        float a = b1[tid];
        for (int k = 0; k < 384; k++) a += comb[k]*W1[k*256 + tid];
        h1s[tid] = fmaxf(a, 0.f);
    }
    __syncthreads();
    if (tid < 128){
        float a = b2[tid];
        for (int k = 0; k < 256; k++) a += h1s[k]*W2[k*H + tid];
        h2g[tid] = fmaxf(a, 0.f);
    }
}

// ---------------- logits + sigmoid ----------------
__global__ __launch_bounds__(256) void k_logits(
    const float* __restrict__ h2g, const float* __restrict__ W3,
    const float* __restrict__ b3, float* __restrict__ out, int T)
{
    __shared__ float h2l[128];
    int tid = threadIdx.x;
    if (tid < 128) h2l[tid] = h2g[tid];
    __syncthreads();
    int t = blockIdx.x*256 + tid;
    if (t >= T) return;
    float a = b3[t];
    #pragma unroll 8
    for (int k = 0; k < 128; k++) a += h2l[k]*W3[(size_t)k*T + t];
    out[t] = 1.f/(1.f + expf(-a));
}

// ---------------- launch ----------------
extern "C" void kernel_launch(void* const* d_in, const int* in_sizes, int n_in,
                              void* d_out, int out_size, void* d_ws, size_t ws_size,
                              hipStream_t stream)
{
    (void)n_in; (void)out_size; (void)ws_size;
    const float* pf    = (const float*)d_in[0];
    const float* tf    = (const float*)d_in[1];
    const float* pe    = (const float*)d_in[2];
    const int*   pre   = (const int*)d_in[3];
    const int*   post  = (const int*)d_in[4];
    const float* W_pe  = (const float*)d_in[5];
    const float* b_pe  = (const float*)d_in[6];
    const float* W_te  = (const float*)d_in[7];
    const float* b_te  = (const float*)d_in[8];
    const float* W_pr  = (const float*)d_in[9];
    const float* b_pr  = (const float*)d_in[10];
    const float* p2t_W = (const float*)d_in[11];
    const float* p2t_b = (const float*)d_in[12];
    const float* t2p_W = (const float*)d_in[13];
    const float* t2p_b = (const float*)d_in[14];
    const float* pu_W  = (const float*)d_in[15];
    const float* pu_b  = (const float*)d_in[16];
    const float* tu_W  = (const float*)d_in[17];
    const float* tu_b  = (const float*)d_in[18];
    const float* pa_W  = (const float*)d_in[19];
    const float* pa_b  = (const float*)d_in[20];
    const float* ta_W  = (const float*)d_in[21];
    const float* ta_b  = (const float*)d_in[22];
    const float* W_pp  = (const float*)d_in[23];
    const float* b_pp  = (const float*)d_in[24];
    const float* W_tp  = (const float*)d_in[25];
    const float* b_tp  = (const float*)d_in[26];
    const float* W1    = (const float*)d_in[27];
    const float* b1    = (const float*)d_in[28];
    const float* W2    = (const float*)d_in[29];
    const float* b2    = (const float*)d_in[30];
    const float* W3    = (const float*)d_in[31];
    const float* b3    = (const float*)d_in[32];

    int P = in_sizes[0];
    int T = in_sizes[1] / 8;
    int E = in_sizes[3] / 2;
    int plen = in_sizes[2];
    int L = in_sizes[11] / (H*H);

    float* ws = (float*)d_ws;
    size_t fP = (size_t)P*H, fT = (size_t)T*H;
    size_t fN = (fP > fT) ? fP : fT;
    int   Nmax = (P > T) ? P : T;

    float* yb = ws;                       // [Nmax] fp32 scores
    float* sc = yb + Nmax;                // 16 softmax slots + small vectors
    float* meanP   = sc + 16;
    float* meanT   = sc + 144;
    float* prefix  = sc + 272;
    float* h2g     = sc + 400;            // end at sc+544 (16B aligned)

    ushort_t* bh = (ushort_t*)(sc + 544);
    ushort_t* place_h = bh;               // [P,128] bf16
    ushort_t* trans_h = place_h + fP;     // [T,128]
    ushort_t* Xb      = trans_h + fT;     // [Nmax,128]
    ushort_t* Mb      = Xb + fN;          // [Nmax,128]
    ushort_t* WTb     = Mb + fN;          // L*98304 bf16 transposed weights

    int* iw = (int*)(WTb + (size_t)L*98304);
    int* cntPre  = iw;                 // [T]
    int* degPre  = cntPre + T;         // [P]
    int* cntPost = degPre + P;         // [P]
    int* degPost = cntPost + P;        // [T]
    int* rpPre   = degPost + T;        // [T+1]
    int* rpPost  = rpPre + (T + 1);    // [P+1]
    int* csrPre  = rpPost + (P + 2);   // [E]
    int* csrPost = csrPre + E;         // [E]
    int* bsumA   = csrPost + E;        // [256]
    int* bsumB   = bsumA + 256;        // [256]

    const int* pre_src  = pre;          const int* pre_dst  = pre + E;
    const int* post_src = post;         const int* post_dst = post + E;

    int g128P = (P + 127)/128, g128T = (T + 127)/128;
    int wtot = L*98304;
    int nbT = (T + 1023)/1024, nbP = (P + 1023)/1024;

    k_init_small<<<1, 128, 0, stream>>>(pe, plen, W_pr, b_pr, prefix, meanP, meanT, sc);
    k_wconv<<<(wtot + 255)/256, 256, 0, stream>>>(p2t_W, t2p_W, tu_W, pu_W, WTb, wtot);
    k_zero_ints<<<512, 256, 0, stream>>>(iw, 2*(P + T));
    k_hist2<<<1024, 256, 0, stream>>>(pre_src, pre_dst, post_src, post_dst, E,
                                      degPre, cntPre, degPost, cntPost);
    k_scan_part<<<nbT, 256, 0, stream>>>(cntPre, T, bsumA);
    k_scan_bsum<<<1, 256, 0, stream>>>(bsumA, nbT);
    k_scan_final<<<nbT, 256, 0, stream>>>(cntPre, T, bsumA, rpPre, E);
    k_scan_part<<<nbP, 256, 0, stream>>>(cntPost, P, bsumB);
    k_scan_bsum<<<1, 256, 0, stream>>>(bsumB, nbP);
    k_scan_final<<<nbP, 256, 0, stream>>>(cntPost, P, bsumB, rpPost, E);
    k_fill2<<<1024, 256, 0, stream>>>(pre_src, pre_dst, post_src, post_dst, E,
                                      rpPre, cntPre, csrPre, rpPost, cntPost, csrPost);

    k_embed_place<<<(P*32 + 255)/256, 256, 0, stream>>>(pf, W_pe, b_pe, place_h, P);
    k_embed_trans<<<(T*32 + 255)/256, 256, 0, stream>>>(tf, W_te, b_te, trans_h, T);

    for (int l = 0; l < L; l++){
        const ushort_t* WTl  = WTb + (size_t)l*98304;
        const ushort_t* p2tT = WTl;
        const ushort_t* t2pT = WTl + 16384;
        const ushort_t* tuT  = WTl + 32768;
        const ushort_t* puT  = WTl + 65536;
        const float* p2tb = p2t_b + (size_t)l*H;
        const float* t2pb = t2p_b + (size_t)l*H;
        const float* pub  = pu_b  + (size_t)l*H;
        const float* tub  = tu_b  + (size_t)l*H;
        const float* paW  = pa_W + (size_t)l*H;   const float* pab = pa_b + l;
        const float* taW  = ta_W + (size_t)l*H;   const float* tab = ta_b + l;
        unsigned* MkA = (unsigned*)(sc + l*4 + 0);   float* SpA = sc + l*4 + 1;
        unsigned* MkB = (unsigned*)(sc + l*4 + 2);   float* SpB = sc + l*4 + 3;
        int last = (l == L-1);

        // phase A: place -> transition (scores over place nodes fused)
        k_gemm_bf<<<g128P, 256, 0, stream>>>(place_h, nullptr, p2tT, p2tb, nullptr, Xb,
                                             P, H, 0, taW, tab, yb, MkA, nullptr);
        k_denom<<<128, 256, 0, stream>>>(degPre, P, yb, MkA, SpA);
        k_gather<<<(T + 15)/16, 256, 0, stream>>>(rpPre, csrPre, T, yb, Xb, Mb, MkA, SpA);

        // phase B: transform from OLD trans_h (+ its scores)
        k_gemm_bf<<<g128T, 256, 0, stream>>>(trans_h, nullptr, t2pT, t2pb, nullptr, Xb,
                                             T, H, 0, paW, pab, yb, MkB, nullptr);
        k_denom<<<128, 256, 0, stream>>>(degPost, T, yb, MkB, SpB);

        // transition update (consumes Mb = trans_msg), in-place
        // last layer: fuse column-sum pooling (meanT accumulator)
        k_gemm_bf<<<g128T, 256, 0, stream>>>(trans_h, Mb, tuT, tub, trans_h, trans_h,
                                             T, 2*H, 1, nullptr, nullptr, nullptr, nullptr,
                                             last ? meanT : nullptr);

        // place messages, then place update in-place (last layer: fuse meanP)
        k_gather<<<(P + 15)/16, 256, 0, stream>>>(rpPost, csrPost, P, yb, Xb, Mb, MkB, SpB);
        k_gemm_bf<<<g128P, 256, 0, stream>>>(place_h, Mb, puT, pub, place_h, place_h,
                                             P, 2*H, 1, nullptr, nullptr, nullptr, nullptr,
                                             last ? meanP : nullptr);
    }

    k_head<<<1, 256, 0, stream>>>(meanP, meanT, 1.f/(float)P, 1.f/(float)T,
                                  W_pp, b_pp, W_tp, b_tp, prefix, W1, b1, W2, b2, h2g);
    k_logits<<<(T + 255)/256, 256, 0, stream>>>(h2g, W3, b3, (float*)d_out, T);
}

// Round 7
// 1086.592 us; speedup vs baseline: 2.2585x; 1.0305x over previous
//
#include <hip/hip_runtime.h>
#include <cstddef>

#define H 128

typedef unsigned short ushort_t;
typedef __attribute__((ext_vector_type(8))) short short8;
typedef __attribute__((ext_vector_type(4))) float floatx4;

// ---------------- helpers ----------------
__device__ __forceinline__ unsigned fkey(float f){
    unsigned u = __float_as_uint(f);
    return (u & 0x80000000u) ? ~u : (u | 0x80000000u);
}
__device__ __forceinline__ float funkey(unsigned k){
    unsigned u = (k & 0x80000000u) ? (k ^ 0x80000000u) : ~k;
    return __uint_as_float(u);
}
__device__ __forceinline__ ushort_t f2bf(float f){
    unsigned u = __float_as_uint(f);
    u += 0x7fffu + ((u >> 16) & 1u);      // round-to-nearest-even
    return (ushort_t)(u >> 16);
}
__device__ __forceinline__ float bf2f(ushort_t h){
    return __uint_as_float(((unsigned)h) << 16);
}

// ---------------- embeddings (write bf16 states) ----------------
__global__ __launch_bounds__(256) void k_embed_place(
    const float* __restrict__ pf, const float* __restrict__ Wpe,
    const float* __restrict__ bpe, ushort_t* __restrict__ out, int P)
{
    int idx = blockIdx.x*256 + threadIdx.x;     // 4-elem group index over P*32
    if (idx >= P*32) return;
    int p = idx >> 5, q = (idx & 31) << 2;
    float v = pf[p];
    float4 w = *(const float4*)(Wpe + q);
    float4 b = *(const float4*)(bpe + q);
    ushort4 o;
    o.x = f2bf(v*w.x + b.x); o.y = f2bf(v*w.y + b.y);
    o.z = f2bf(v*w.z + b.z); o.w = f2bf(v*w.w + b.w);
    *(ushort4*)(out + (size_t)p*H + q) = o;
}

__global__ __launch_bounds__(256) void k_embed_trans(
    const float* __restrict__ tf, const float* __restrict__ Wte,
    const float* __restrict__ bte, ushort_t* __restrict__ out, int T)
{
    __shared__ float Wl[8*H];
    __shared__ float Bl[H];
    int tid = threadIdx.x;
    #pragma unroll
    for (int t = 0; t < 4; t++) Wl[tid + t*256] = Wte[tid + t*256];
    if (tid < H) Bl[tid] = bte[tid];
    __syncthreads();
    int idx = blockIdx.x*256 + tid;
    if (idx >= T*32) return;
    int t = idx >> 5, q = (idx & 31) << 2;
    float4 acc = *(float4*)(&Bl[q]);
    #pragma unroll
    for (int k = 0; k < 8; k++){
        float s = tf[(size_t)t*8 + k];
        float4 w = *(float4*)(&Wl[k*H + q]);
        acc.x += s*w.x; acc.y += s*w.y; acc.z += s*w.z; acc.w += s*w.w;
    }
    ushort4 o;
    o.x = f2bf(acc.x); o.y = f2bf(acc.y); o.z = f2bf(acc.z); o.w = f2bf(acc.w);
    *(ushort4*)(out + (size_t)t*H + q) = o;
}

// prefix embedding + zero small accumulators + all softmax slots
__global__ void k_init_small(const float* __restrict__ pe, int plen,
                             const float* __restrict__ Wpr, const float* __restrict__ bpr,
                             float* __restrict__ prefix, float* __restrict__ meanP,
                             float* __restrict__ meanT, float* __restrict__ slots)
{
    int c = threadIdx.x;  // 128 threads
    float a = bpr[c];
    for (int k = 0; k < plen; k++) a += pe[k]*Wpr[k*H + c];
    prefix[c] = a;
    meanP[c] = 0.f;
    meanT[c] = 0.f;
    if (c < 16) slots[c] = 0.f;   // fkey-space 0 == -inf
}

// ---------------- weight transpose + bf16 convert ----------------
// per layer l: WT layout [p2tT 128x128][t2pT 128x128][tuT 128x256][puT 128x256]
__global__ __launch_bounds__(256) void k_wconv(
    const float* __restrict__ p2t_W, const float* __restrict__ t2p_W,
    const float* __restrict__ tu_W,  const float* __restrict__ pu_W,
    ushort_t* __restrict__ WT, int total)
{
    int e = blockIdx.x*256 + threadIdx.x;
    if (e >= total) return;
    int l = e / 98304, o = e - l*98304;
    const float* src; int K, oo;
    if (o < 16384)      { src = p2t_W + (size_t)l*16384; K = 128; oo = o; }
    else if (o < 32768) { src = t2p_W + (size_t)l*16384; K = 128; oo = o - 16384; }
    else if (o < 65536) { src = tu_W  + (size_t)l*32768; K = 256; oo = o - 32768; }
    else                { src = pu_W  + (size_t)l*32768; K = 256; oo = o - 65536; }
    int n = oo / K, k = oo - n*K;
    WT[e] = f2bf(src[(size_t)k*H + n]);
}

// ---------------- CSR build ----------------
__global__ __launch_bounds__(256) void k_zero_ints(int* __restrict__ p, int n)
{
    int i = blockIdx.x*256 + threadIdx.x;
    int stride = gridDim.x*256;
    for (; i < n; i += stride) p[i] = 0;
}

__global__ __launch_bounds__(256) void k_hist2(
    const int* __restrict__ preS, const int* __restrict__ preD,
    const int* __restrict__ postS, const int* __restrict__ postD, int E,
    int* __restrict__ degPre, int* __restrict__ cntPre,
    int* __restrict__ degPost, int* __restrict__ cntPost)
{
    int i = blockIdx.x*256 + threadIdx.x;
    int stride = gridDim.x*256;
    for (; i < E; i += stride){
        atomicAdd(&degPre[preS[i]], 1);
        atomicAdd(&cntPre[preD[i]], 1);
        atomicAdd(&degPost[postS[i]], 1);
        atomicAdd(&cntPost[postD[i]], 1);
    }
}

// ---- multi-block exclusive scan (chunk = 1024 per block) ----
__global__ __launch_bounds__(256) void k_scan_part(
    const int* __restrict__ cnt, int N, int* __restrict__ bsum)
{
    __shared__ int wsum[4];
    int tid = threadIdx.x, lane = tid & 63, wid = tid >> 6;
    int base = blockIdx.x*1024 + tid*4;
    int4 v = make_int4(0,0,0,0);
    if (base + 3 < N) v = *(const int4*)(cnt + base);
    else {
        if (base+0 < N) v.x = cnt[base+0];
        if (base+1 < N) v.y = cnt[base+1];
        if (base+2 < N) v.z = cnt[base+2];
    }
    int s = v.x + v.y + v.z + v.w;
    #pragma unroll
    for (int o = 1; o < 64; o <<= 1) s += __shfl_xor(s, o);
    if (lane == 0) wsum[wid] = s;
    __syncthreads();
    if (tid == 0) bsum[blockIdx.x] = wsum[0] + wsum[1] + wsum[2] + wsum[3];
}

__global__ __launch_bounds__(256) void k_scan_bsum(int* __restrict__ bsum, int nb)
{
    __shared__ int wsum[4];
    int tid = threadIdx.x, lane = tid & 63, wid = tid >> 6;
    int x = (tid < nb) ? bsum[tid] : 0;
    int inc = x;
    #pragma unroll
    for (int o = 1; o < 64; o <<= 1){
        int u = __shfl_up(inc, o);
        if (lane >= o) inc += u;
    }
    if (lane == 63) wsum[wid] = inc;
    __syncthreads();
    int woff = 0;
    if (wid > 0) woff += wsum[0];
    if (wid > 1) woff += wsum[1];
    if (wid > 2) woff += wsum[2];
    if (tid < nb) bsum[tid] = woff + inc - x;
}

__global__ __launch_bounds__(256) void k_scan_final(
    int* __restrict__ cnt, int N, const int* __restrict__ bsum,
    int* __restrict__ rp, int E)
{
    __shared__ int wsum[4];
    int tid = threadIdx.x, lane = tid & 63, wid = tid >> 6;
    int base = blockIdx.x*1024 + tid*4;
    int4 v = make_int4(0,0,0,0);
    if (base + 3 < N) v = *(const int4*)(cnt + base);
    else {
        if (base+0 < N) v.x = cnt[base+0];
        if (base+1 < N) v.y = cnt[base+1];
        if (base+2 < N) v.z = cnt[base+2];
    }
    int t0 = v.x, t1 = t0 + v.y, t2 = t1 + v.z, t3 = t2 + v.w;
    int inc = t3;
    #pragma unroll
    for (int o = 1; o < 64; o <<= 1){
        int u = __shfl_up(inc, o);
        if (lane >= o) inc += u;
    }
    if (lane == 63) wsum[wid] = inc;
    __syncthreads();
    int woff = 0;
    if (wid > 0) woff += wsum[0];
    if (wid > 1) woff += wsum[1];
    if (wid > 2) woff += wsum[2];
    int off = bsum[blockIdx.x] + woff + inc - t3;
    if (base+0 < N){ rp[base+0] = off;      cnt[base+0] = 0; }
    if (base+1 < N){ rp[base+1] = off + t0; cnt[base+1] = 0; }
    if (base+2 < N){ rp[base+2] = off + t1; cnt[base+2] = 0; }
    if (base+3 < N){ rp[base+3] = off + t2; cnt[base+3] = 0; }
    if (blockIdx.x == 0 && tid == 0) rp[N] = E;
}

__global__ __launch_bounds__(256) void k_fill2(
    const int* __restrict__ preS, const int* __restrict__ preD,
    const int* __restrict__ postS, const int* __restrict__ postD, int E,
    const int* __restrict__ rpPre, int* __restrict__ curPre, int* __restrict__ csrPre,
    const int* __restrict__ rpPost, int* __restrict__ curPost, int* __restrict__ csrPost)
{
    int i = blockIdx.x*256 + threadIdx.x;
    int stride = gridDim.x*256;
    for (; i < E; i += stride){
        int d = preD[i];
        csrPre[rpPre[d] + atomicAdd(&curPre[d], 1)] = preS[i];
        int d2 = postD[i];
        csrPost[rpPost[d2] + atomicAdd(&curPost[d2], 1)] = postS[i];
    }
}

// ---------------- wave-tile bf16 MFMA GEMM (barrier-free main loop) ----------
// out[M,128] = maybe_relu( maybe(resid) + [A1|A2] @ W + bias ), W in LDS (whole).
// Each wave owns independent 16-row tiles (grid-stride). A-fragments loaded
// directly global->VGPR (16B/lane, natural MFMA A layout). No syncthreads in
// the main loop -> deep memory pipelining across waves.
// Optional fused score (aw): y[row], block max -> Mkey (one atomic per block).
// Optional fused column-sum (colsum): pooling accumulated in registers,
// flushed once per block.
template<int NK>
__global__ __launch_bounds__(256) void k_gemm_wt(
    const ushort_t* __restrict__ A1, const ushort_t* __restrict__ A2,
    const ushort_t* __restrict__ WT, const float* __restrict__ bias,
    const ushort_t* __restrict__ resid, ushort_t* __restrict__ out,
    int M, int relu,
    const float* __restrict__ aw, const float* __restrict__ abp,
    float* __restrict__ y, unsigned* __restrict__ Mkey,
    float* __restrict__ colsum)
{
    constexpr int K  = NK*32;
    constexpr int KS = K + 8;             // pad: stride 4 banks -> 2-way (free)
    __shared__ ushort_t Ws[128*KS];
    __shared__ float bl[H];
    __shared__ float awl[H];
    __shared__ float csum[H];
    __shared__ unsigned mkk;
    int tid = threadIdx.x;
    int lane = tid & 63, wid = tid >> 6;
    int quad = lane >> 4, l15 = lane & 15;

    // stage full W (128 x K) once
    for (int i = tid; i < 128*(K/8); i += 256){
        int n  = (NK == 8) ? (i >> 5) : (i >> 4);
        int ko = (NK == 8) ? ((i & 31) << 3) : ((i & 15) << 3);
        *(int4*)(&Ws[n*KS + ko]) = *(const int4*)(WT + (size_t)n*K + ko);
    }
    if (tid < H){
        bl[tid]  = bias[tid];
        awl[tid] = aw ? aw[tid] : 0.f;
        csum[tid] = 0.f;
    }
    if (tid == 0) mkk = 0u;
    __syncthreads();

    const bool has_aw = (aw != nullptr);
    const bool has_cs = (colsum != nullptr);
    int tiles = (M + 15) >> 4;
    int gw = blockIdx.x*4 + wid, nw = gridDim.x*4;
    float ab = has_aw ? abp[0] : 0.f;
    float wmax = -3.402823466e38f;
    float cs[8] = {0.f,0.f,0.f,0.f,0.f,0.f,0.f,0.f};

    for (int t = gw; t < tiles; t += nw){
        int row0 = t << 4;
        int rA = row0 + l15; if (rA >= M) rA = M - 1;
        short8 afr[NK];
        #pragma unroll
        for (int kk = 0; kk < NK; kk++){
            const ushort_t* sp;
            if (NK == 8 && kk >= 4) sp = A2 + (size_t)rA*H + (kk-4)*32 + quad*8;
            else                    sp = A1 + (size_t)rA*H + kk*32 + quad*8;
            afr[kk] = *(const short8*)sp;
        }
        floatx4 acc[8];
        #pragma unroll
        for (int j = 0; j < 8; j++) acc[j] = (floatx4)0.f;
        #pragma unroll
        for (int j = 0; j < 8; j++){
            int nrow = j*16 + l15;
            #pragma unroll
            for (int kk = 0; kk < NK; kk++){
                short8 bfr = *(const short8*)(&Ws[nrow*KS + kk*32 + quad*8]);
                acc[j] = __builtin_amdgcn_mfma_f32_16x16x32_bf16(afr[kk], bfr, acc[j], 0,0,0);
            }
        }
        // epilogue: row = row0 + quad*4 + rr, col = j*16 + l15
        float pr[4] = {0.f,0.f,0.f,0.f};
        #pragma unroll
        for (int j = 0; j < 8; j++){
            int col = j*16 + l15;
            float bc = bl[col];
            float awc = awl[col];
            #pragma unroll
            for (int rr = 0; rr < 4; rr++){
                int grow = row0 + quad*4 + rr;
                bool ok = (grow < M);
                int gr = ok ? grow : (M-1);
                float v = acc[j][rr] + bc;
                if (resid) v += bf2f(resid[(size_t)gr*H + col]);
                if (relu)  v = fmaxf(v, 0.f);
                if (ok){
                    out[(size_t)grow*H + col] = f2bf(v);
                    pr[rr] += v * awc;
                    if (has_cs) cs[j] += v;
                }
            }
        }
        if (has_aw){
            #pragma unroll
            for (int rr = 0; rr < 4; rr++){
                float p = pr[rr];
                p += __shfl_xor(p, 1); p += __shfl_xor(p, 2);
                p += __shfl_xor(p, 4); p += __shfl_xor(p, 8);
                int grow = row0 + quad*4 + rr;
                if (grow < M){
                    float s = p + ab;
                    if (l15 == 0) y[grow] = s;
                    wmax = fmaxf(wmax, s);
                }
            }
        }
    }
    // block-level flush (one barrier, once per kernel)
    if (has_aw){
        float m = wmax;
        m = fmaxf(m, __shfl_xor(m, 16));
        m = fmaxf(m, __shfl_xor(m, 32));
        if (lane == 0) atomicMax(&mkk, fkey(m));
    }
    if (has_cs){
        #pragma unroll
        for (int j = 0; j < 8; j++){
            float v = cs[j];
            v += __shfl_xor(v, 16);
            v += __shfl_xor(v, 32);
            if (quad == 0) atomicAdd(&csum[j*16 + l15], v);
        }
    }
    __syncthreads();
    if (has_cs && tid < H) atomicAdd(&colsum[tid], csum[tid]);
    if (has_aw && tid == 0) atomicMax(Mkey, mkk);
}

// ---------------- softmax denominator: sum over nodes of deg * exp(y - M) -----
__global__ __launch_bounds__(256) void k_denom(
    const int* __restrict__ deg, int N, const float* __restrict__ y,
    const unsigned* __restrict__ Mkey, float* __restrict__ Sp)
{
    __shared__ float red[256];
    int tid = threadIdx.x;
    int gid = blockIdx.x*256 + tid, stride = gridDim.x*256;
    float Mv = funkey(Mkey[0]);
    float ls = 0.f;
    for (int n = gid; n < N; n += stride){
        int d = deg[n];
        if (d) ls += (float)d * expf(y[n] - Mv);
    }
    red[tid] = ls;
    __syncthreads();
    for (int s = 128; s > 0; s >>= 1){
        if (tid < s) red[tid] += red[tid + s];
        __syncthreads();
    }
    if (tid == 0) atomicAdd(Sp, red[0]);
}

// accumulate 8 bf16 (one int4) into 8 fp32 with weight
__device__ __forceinline__ void acc8(float* a, int4 u, float wgt){
    a[0] += wgt*__uint_as_float(((unsigned)u.x) << 16);
    a[1] += wgt*__uint_as_float(((unsigned)u.x) & 0xffff0000u);
    a[2] += wgt*__uint_as_float(((unsigned)u.y) << 16);
    a[3] += wgt*__uint_as_float(((unsigned)u.y) & 0xffff0000u);
    a[4] += wgt*__uint_as_float(((unsigned)u.z) << 16);
    a[5] += wgt*__uint_as_float(((unsigned)u.z) & 0xffff0000u);
    a[6] += wgt*__uint_as_float(((unsigned)u.w) << 16);
    a[7] += wgt*__uint_as_float(((unsigned)u.w) & 0xffff0000u);
}

// ---------------- CSR gather: 16-lane row groups, int4 loads, 2-edge unroll ---
__global__ __launch_bounds__(256) void k_gather(
    const int* __restrict__ rp, const int* __restrict__ csr, int Nrow,
    const float* __restrict__ y, const ushort_t* __restrict__ X,
    ushort_t* __restrict__ Mb, const unsigned* __restrict__ Mkey,
    const float* __restrict__ Sp)
{
    int tid = threadIdx.x;
    int g = tid >> 4, gl = tid & 15;          // 16 groups x 16 lanes
    int r = blockIdx.x*16 + g;
    if (r >= Nrow) return;
    float Mv = funkey(Mkey[0]);
    float invS = 1.f / Sp[0];
    int j0 = rp[r], j1 = rp[r+1];
    const int4* X4 = (const int4*)X;          // row = 16 int4 (128 bf16)
    float a[8] = {0.f,0.f,0.f,0.f,0.f,0.f,0.f,0.f};
    int j = j0;
    for (; j + 1 < j1; j += 2){
        int s0 = csr[j], s1 = csr[j+1];
        float e0 = expf(y[s0] - Mv);
        float e1 = expf(y[s1] - Mv);
        int4 u0 = X4[(size_t)s0*16 + gl];
        int4 u1 = X4[(size_t)s1*16 + gl];
        acc8(a, u0, e0);
        acc8(a, u1, e1);
    }
    if (j < j1){
        int s0 = csr[j];
        float e0 = expf(y[s0] - Mv);
        int4 u0 = X4[(size_t)s0*16 + gl];
        acc8(a, u0, e0);
    }
    int4 o;
    o.x = (int)((((unsigned)f2bf(a[1]*invS)) << 16) | (unsigned)f2bf(a[0]*invS));
    o.y = (int)((((unsigned)f2bf(a[3]*invS)) << 16) | (unsigned)f2bf(a[2]*invS));
    o.z = (int)((((unsigned)f2bf(a[5]*invS)) << 16) | (unsigned)f2bf(a[4]*invS));
    o.w = (int)((((unsigned)f2bf(a[7]*invS)) << 16) | (unsigned)f2bf(a[6]*invS));
    ((int4*)Mb)[(size_t)r*16 + gl] = o;
}

// ---------------- tiny MLP head ----------------
__global__ __launch_bounds__(256) void k_head(
    const float* __restrict__ meanP, const float* __restrict__ meanT,
    float invP, float invT,
    const float* __restrict__ Wpp, const float* __restrict__ bpp,
    const float* __restrict__ Wtp, const float* __restrict__ btp,
    const float* __restrict__ prefix,
    const float* __restrict__ W1, const float* __restrict__ b1,
    const float* __restrict__ W2, const float* __restrict__ b2,
    float* __restrict__ h2g)
{
    __shared__ float comb[384];
    __shared__ float h1s[256];
    int tid = threadIdx.x;
    if (tid < 128){
        float a = bpp[tid];
        for (int k = 0; k < 128; k++) a += meanP[k]*invP*Wpp[k*H + tid];
        comb[tid] = a;
        comb[256 + tid] = prefix[tid];
    } else {
        int c = tid - 128;
        float a = btp[c];
        for (int k = 0; k < 128; k++) a += meanT[k]*invT*Wtp[k*H + c];
        comb[128 + c] = a;
    }
    __syncthreads();
    {
        float a = b1[tid];
        for (int k = 0; k < 384; k++) a += comb[k]*W1[k*256 + tid];
        h1s[tid] = fmaxf(a, 0.f);
    }
    __syncthreads();
    if (tid < 128){
        float a = b2[tid];
        for (int k = 0; k < 256; k++) a += h1s[k]*W2[k*H + tid];
        h2g[tid] = fmaxf(a, 0.f);
    }
}

// ---------------- logits + sigmoid ----------------
__global__ __launch_bounds__(256) void k_logits(
    const float* __restrict__ h2g, const float* __restrict__ W3,
    const float* __restrict__ b3, float* __restrict__ out, int T)
{
    __shared__ float h2l[128];
    int tid = threadIdx.x;
    if (tid < 128) h2l[tid] = h2g[tid];
    __syncthreads();
    int t = blockIdx.x*256 + tid;
    if (t >= T) return;
    float a = b3[t];
    #pragma unroll 8
    for (int k = 0; k < 128; k++) a += h2l[k]*W3[(size_t)k*T + t];
    out[t] = 1.f/(1.f + expf(-a));
}

// ---------------- launch ----------------
extern "C" void kernel_launch(void* const* d_in, const int* in_sizes, int n_in,
                              void* d_out, int out_size, void* d_ws, size_t ws_size,
                              hipStream_t stream)
{
    (void)n_in; (void)out_size; (void)ws_size;
    const float* pf    = (const float*)d_in[0];
    const float* tf    = (const float*)d_in[1];
    const float* pe    = (const float*)d_in[2];
    const int*   pre   = (const int*)d_in[3];
    const int*   post  = (const int*)d_in[4];
    const float* W_pe  = (const float*)d_in[5];
    const float* b_pe  = (const float*)d_in[6];
    const float* W_te  = (const float*)d_in[7];
    const float* b_te  = (const float*)d_in[8];
    const float* W_pr  = (const float*)d_in[9];
    const float* b_pr  = (const float*)d_in[10];
    const float* p2t_W = (const float*)d_in[11];
    const float* p2t_b = (const float*)d_in[12];
    const float* t2p_W = (const float*)d_in[13];
    const float* t2p_b = (const float*)d_in[14];
    const float* pu_W  = (const float*)d_in[15];
    const float* pu_b  = (const float*)d_in[16];
    const float* tu_W  = (const float*)d_in[17];
    const float* tu_b  = (const float*)d_in[18];
    const float* pa_W  = (const float*)d_in[19];
    const float* pa_b  = (const float*)d_in[20];
    const float* ta_W  = (const float*)d_in[21];
    const float* ta_b  = (const float*)d_in[22];
    const float* W_pp  = (const float*)d_in[23];
    const float* b_pp  = (const float*)d_in[24];
    const float* W_tp  = (const float*)d_in[25];
    const float* b_tp  = (const float*)d_in[26];
    const float* W1    = (const float*)d_in[27];
    const float* b1    = (const float*)d_in[28];
    const float* W2    = (const float*)d_in[29];
    const float* b2    = (const float*)d_in[30];
    const float* W3    = (const float*)d_in[31];
    const float* b3    = (const float*)d_in[32];

    int P = in_sizes[0];
    int T = in_sizes[1] / 8;
    int E = in_sizes[3] / 2;
    int plen = in_sizes[2];
    int L = in_sizes[11] / (H*H);

    float* ws = (float*)d_ws;
    size_t fP = (size_t)P*H, fT = (size_t)T*H;
    size_t fN = (fP > fT) ? fP : fT;
    int   Nmax = (P > T) ? P : T;

    float* yb = ws;                       // [Nmax] fp32 scores
    float* sc = yb + Nmax;                // 16 softmax slots + small vectors
    float* meanP   = sc + 16;
    float* meanT   = sc + 144;
    float* prefix  = sc + 272;
    float* h2g     = sc + 400;            // end at sc+544 (16B aligned)

    ushort_t* bh = (ushort_t*)(sc + 544);
    ushort_t* place_h = bh;               // [P,128] bf16
    ushort_t* trans_h = place_h + fP;     // [T,128]
    ushort_t* Xb      = trans_h + fT;     // [Nmax,128]
    ushort_t* Mb      = Xb + fN;          // [Nmax,128]
    ushort_t* WTb     = Mb + fN;          // L*98304 bf16 transposed weights

    int* iw = (int*)(WTb + (size_t)L*98304);
    int* cntPre  = iw;                 // [T]
    int* degPre  = cntPre + T;         // [P]
    int* cntPost = degPre + P;         // [P]
    int* degPost = cntPost + P;        // [T]
    int* rpPre   = degPost + T;        // [T+1]
    int* rpPost  = rpPre + (T + 1);    // [P+1]
    int* csrPre  = rpPost + (P + 2);   // [E]
    int* csrPost = csrPre + E;         // [E]
    int* bsumA   = csrPost + E;        // [256]
    int* bsumB   = bsumA + 256;        // [256]

    const int* pre_src  = pre;          const int* pre_dst  = pre + E;
    const int* post_src = post;         const int* post_dst = post + E;

    int wtot = L*98304;
    int nbT = (T + 1023)/1024, nbP = (P + 1023)/1024;

    k_init_small<<<1, 128, 0, stream>>>(pe, plen, W_pr, b_pr, prefix, meanP, meanT, sc);
    k_wconv<<<(wtot + 255)/256, 256, 0, stream>>>(p2t_W, t2p_W, tu_W, pu_W, WTb, wtot);
    k_zero_ints<<<512, 256, 0, stream>>>(iw, 2*(P + T));
    k_hist2<<<1024, 256, 0, stream>>>(pre_src, pre_dst, post_src, post_dst, E,
                                      degPre, cntPre, degPost, cntPost);
    k_scan_part<<<nbT, 256, 0, stream>>>(cntPre, T, bsumA);
    k_scan_bsum<<<1, 256, 0, stream>>>(bsumA, nbT);
    k_scan_final<<<nbT, 256, 0, stream>>>(cntPre, T, bsumA, rpPre, E);
    k_scan_part<<<nbP, 256, 0, stream>>>(cntPost, P, bsumB);
    k_scan_bsum<<<1, 256, 0, stream>>>(bsumB, nbP);
    k_scan_final<<<nbP, 256, 0, stream>>>(cntPost, P, bsumB, rpPost, E);
    k_fill2<<<1024, 256, 0, stream>>>(pre_src, pre_dst, post_src, post_dst, E,
                                      rpPre, cntPre, csrPre, rpPost, cntPost, csrPost);

    k_embed_place<<<(P*32 + 255)/256, 256, 0, stream>>>(pf, W_pe, b_pe, place_h, P);
    k_embed_trans<<<(T*32 + 255)/256, 256, 0, stream>>>(tf, W_te, b_te, trans_h, T);

    for (int l = 0; l < L; l++){
        const ushort_t* WTl  = WTb + (size_t)l*98304;
        const ushort_t* p2tT = WTl;
        const ushort_t* t2pT = WTl + 16384;
        const ushort_t* tuT  = WTl + 32768;
        const ushort_t* puT  = WTl + 65536;
        const float* p2tb = p2t_b + (size_t)l*H;
        const float* t2pb = t2p_b + (size_t)l*H;
        const float* pub  = pu_b  + (size_t)l*H;
        const float* tub  = tu_b  + (size_t)l*H;
        const float* paW  = pa_W + (size_t)l*H;   const float* pab = pa_b + l;
        const float* taW  = ta_W + (size_t)l*H;   const float* tab = ta_b + l;
        unsigned* MkA = (unsigned*)(sc + l*4 + 0);   float* SpA = sc + l*4 + 1;
        unsigned* MkB = (unsigned*)(sc + l*4 + 2);   float* SpB = sc + l*4 + 3;
        int last = (l == L-1);

        // phase A: place -> transition (scores over place nodes fused)
        k_gemm_wt<4><<<1024, 256, 0, stream>>>(place_h, nullptr, p2tT, p2tb, nullptr, Xb,
                                               P, 0, taW, tab, yb, MkA, nullptr);
        k_denom<<<128, 256, 0, stream>>>(degPre, P, yb, MkA, SpA);
        k_gather<<<(T + 15)/16, 256, 0, stream>>>(rpPre, csrPre, T, yb, Xb, Mb, MkA, SpA);

        // phase B: transform from OLD trans_h (+ its scores)
        k_gemm_wt<4><<<1024, 256, 0, stream>>>(trans_h, nullptr, t2pT, t2pb, nullptr, Xb,
                                               T, 0, paW, pab, yb, MkB, nullptr);
        k_denom<<<128, 256, 0, stream>>>(degPost, T, yb, MkB, SpB);

        // transition update (consumes Mb = trans_msg), in-place
        // last layer: fuse column-sum pooling (meanT accumulator)
        k_gemm_wt<8><<<512, 256, 0, stream>>>(trans_h, Mb, tuT, tub, trans_h, trans_h,
                                              T, 1, nullptr, nullptr, nullptr, nullptr,
                                              last ? meanT : nullptr);

        // place messages, then place update in-place (last layer: fuse meanP)
        k_gather<<<(P + 15)/16, 256, 0, stream>>>(rpPost, csrPost, P, yb, Xb, Mb, MkB, SpB);
        k_gemm_wt<8><<<512, 256, 0, stream>>>(place_h, Mb, puT, pub, place_h, place_h,
                                              P, 1, nullptr, nullptr, nullptr, nullptr,
                                              last ? meanP : nullptr);
    }

    k_head<<<1, 256, 0, stream>>>(meanP, meanT, 1.f/(float)P, 1.f/(float)T,
                                  W_pp, b_pp, W_tp, b_tp, prefix, W1, b1, W2, b2, h2g);
    k_logits<<<(T + 255)/256, 256, 0, stream>>>(h2g, W3, b3, (float*)d_out, T);
}